// Round 6
// baseline (149.552 us; speedup 1.0000x reference)
//
#include <hip/hip_runtime.h>
#include <hip/hip_bf16.h>
#include <math.h>

#define B_    4
#define CIN_  64
#define COUT_ 64
#define H_    128
#define W_    160
#define HW_   (H_*W_)
#define NPIX_ (B_*HW_)      // 81920
#define XC_   72            // NHWC channel stride: x(64) + sim(8)
#define OMC_  28            // om channels padded (27 used)
#define EPS_  1e-8f
#define NCH_  21            // cm K-chunks: ceil(648/32)

typedef float  f4    __attribute__((ext_vector_type(4)));
typedef float  f32x4 __attribute__((ext_vector_type(4)));
typedef short  bf16x8 __attribute__((ext_vector_type(8)));

static __device__ __forceinline__ short f2bf_s(float f) {
    __hip_bfloat16 h = __float2bfloat16(f);
    return *reinterpret_cast<short*>(&h);
}

// ---------------------------------------------------------------------------
// prep:
//  wdT[k][o][c] bf16 (9*64*64): PLAIN layout dcn weights (waves read frags
//    directly from L2; no LDS, no swizzle needed).
//  cwB[ch][o][kk] bf16 (21*32*32): cm weights per K-chunk, zero-padded.
// ---------------------------------------------------------------------------
__global__ __launch_bounds__(256) void prep_kernel(const float* __restrict__ wt,
                                                   const float* __restrict__ cmw,
                                                   short* __restrict__ wdT,
                                                   short* __restrict__ cwB)
{
    int i = blockIdx.x * 256 + threadIdx.x;
    if (i < 9*4096) {
        int k = i >> 12, r = i & 4095, o = r >> 6, c = r & 63;
        wdT[i] = f2bf_s(wt[(o*64 + c)*9 + k]);
    }
    int j = i - 9*4096;
    if (j >= 0 && j < NCH_*1024) {
        int cch = j >> 10, r = j & 1023, o = r >> 5, kk = r & 31;
        int k = cch*32 + kk;
        short v = 0;
        if (o < 27 && k < 648) {
            int tap = k / 72, ch = k - (k/72)*72;
            v = f2bf_s(cmw[((size_t)o*72 + ch)*9 + tap]);
        }
        cwB[j] = v;
    }
}

// ---------------------------------------------------------------------------
// xpose: NCHW x -> NHWC xs[px][0..63]  (channels 64..71 filled by sim_kernel)
// ---------------------------------------------------------------------------
__global__ __launch_bounds__(128) void xpose_kernel(const float* __restrict__ x,
                                                    float* __restrict__ xs)
{
    __shared__ float l[128][65];
    const int t = threadIdx.x;
    const int px0 = blockIdx.x * 128;
    const int b = px0 / HW_, p0 = px0 % HW_;
    for (int c = 0; c < 64; c++)
        l[t][c] = x[((size_t)(b*64 + c))*HW_ + p0 + t];
    __syncthreads();
#pragma unroll
    for (int rep = 0; rep < 16; rep++) {
        int pxl = (t >> 4) + rep*8;
        int c4  = (t & 15) * 4;
        f4 v = { l[pxl][c4], l[pxl][c4+1], l[pxl][c4+2], l[pxl][c4+3] };
        *reinterpret_cast<f4*>(&xs[(size_t)(px0+pxl)*XC_ + c4]) = v;
    }
}

// ---------------------------------------------------------------------------
// sim: 2 threads/pixel (channel halves), shfl_xor(1) combine. Grid 640.
// ---------------------------------------------------------------------------
__global__ __launch_bounds__(256, 2) void sim_kernel(float* __restrict__ xs)
{
    const int t = threadIdx.x;
    const int wg = blockIdx.x;
    const int sw = (wg & 7) * 80 + (wg >> 3);               // XCD-contiguous
    const int px = sw * 128 + (t >> 1);
    const int h = t & 1;
    const int w = px % W_, hh = (px / W_) % H_, b = px / HW_;

    const float* cen = xs + (size_t)px * XC_ + h*32;
    f4 cv[8]; float ncc = 0.f;
#pragma unroll
    for (int q = 0; q < 8; q++) {
        cv[q] = *reinterpret_cast<const f4*>(cen + q*4);
#pragma unroll
        for (int j = 0; j < 4; j++) ncc = fmaf(cv[q][j], cv[q][j], ncc);
    }

    const int kyA[8] = {-1,-1,-1, 0, 0, 1, 1, 1};
    const int kxA[8] = {-1, 0, 1,-1, 1,-1, 0, 1};
    float dot[8], nn[8];
#pragma unroll
    for (int n = 0; n < 8; n++) {
        int hn = hh + kyA[n], wn = w + kxA[n];
        bool v = (hn >= 0) & (hn < H_) & (wn >= 0) & (wn < W_);
        float msk = v ? 1.f : 0.f;
        const float* nb = xs + (size_t)(b*HW_ + min(max(hn,0),H_-1)*W_ + min(max(wn,0),W_-1))*XC_ + h*32;
        float d = 0.f, s2 = 0.f;
#pragma unroll
        for (int q = 0; q < 8; q++) {
            f4 qv = *reinterpret_cast<const f4*>(nb + q*4);
#pragma unroll
            for (int j = 0; j < 4; j++) {
                float vv = qv[j] * msk;
                d  = fmaf(cv[q][j], vv, d);
                s2 = fmaf(vv, vv, s2);
            }
        }
        dot[n] = d; nn[n] = s2;
    }
    ncc += __shfl_xor(ncc, 1);
    const float ncr = 1.f / fmaxf(sqrtf(ncc), EPS_);
    float res[8];
#pragma unroll
    for (int n = 0; n < 8; n++) {
        float dt = dot[n] + __shfl_xor(dot[n], 1);
        float s2 = nn[n]  + __shfl_xor(nn[n], 1);
        res[n] = dt * ncr / fmaxf(sqrtf(s2), EPS_);
    }
    f4 r = { h ? res[4] : res[0], h ? res[5] : res[1],
             h ? res[6] : res[2], h ? res[7] : res[3] };
    *reinterpret_cast<f4*>(xs + (size_t)px * XC_ + 64 + h*4) = r;
}

// ---------------------------------------------------------------------------
// cm: 3x3 conv 72->27 as bf16 MFMA implicit GEMM — BARRIER-FREE / LDS-FREE.
// Lane (fr,fq) of wave wv gathers exactly its own MFMA A-fragment
// (px = px0+wv*16+fr, k-slice fq*8 of the chunk); W-frags read straight
// from cwB in L2. 1-chunk-ahead software pipeline in loop-carried regs.
// ---------------------------------------------------------------------------
__global__ __launch_bounds__(256, 2) void cm_kernel(const float* __restrict__ xs,
                                                    const short* __restrict__ cwB,
                                                    const float* __restrict__ cmb,
                                                    float* __restrict__ om)
{
    const int t  = threadIdx.x;
    const int wg = blockIdx.x;
    const int sw = (wg & 7) * 160 + (wg >> 3);              // XCD-contiguous
    const int px0 = sw * 64;
    const int lane = t & 63, wv = t >> 6;
    const int fr = lane & 15, fq = lane >> 4;

    const int pxs = px0 + wv*16 + fr;
    const int wsx = pxs % W_, hs = (pxs / W_) % H_, bs = pxs / HW_;
    const size_t xrow = (size_t)bs * HW_;

    f32x4 acc[2];
    acc[0] = (f32x4){0.f,0.f,0.f,0.f};
    acc[1] = (f32x4){0.f,0.f,0.f,0.f};

    f4 G[2]; bf16x8 WF[2]; float msk;

#define CM_ISSUE_G(CH) do {                                                   \
    int k0_ = (CH)*32 + fq*8;                                                 \
    int tap_ = (k0_ * 911) >> 16;                                             \
    float valid_ = (tap_ < 9) ? 1.f : 0.f;                                    \
    tap_ = min(tap_, 8);                                                      \
    int ch_ = min(max(k0_ - tap_*72, 0), 64);                                 \
    int t3_ = (tap_ * 11) >> 5;                                               \
    int hy_ = hs + t3_ - 1, wx_ = wsx + (tap_ - t3_*3) - 1;                   \
    bool v_ = (hy_ >= 0) & (hy_ < H_) & (wx_ >= 0) & (wx_ < W_);              \
    msk = (v_ ? 1.f : 0.f) * valid_;                                          \
    const float* src_ = xs + (size_t)(xrow + min(max(hy_,0),H_-1)*W_          \
                                      + min(max(wx_,0),W_-1))*XC_ + ch_;      \
    G[0] = *reinterpret_cast<const f4*>(src_);                                \
    G[1] = *reinterpret_cast<const f4*>(src_ + 4);                            \
  } while(0)

#define CM_ISSUE_W(CH) do {                                                   \
    const short* wp_ = cwB + (CH)*1024 + fr*32 + fq*8;                        \
    WF[0] = *reinterpret_cast<const bf16x8*>(wp_);                            \
    WF[1] = *reinterpret_cast<const bf16x8*>(wp_ + 512);                      \
  } while(0)

    CM_ISSUE_G(0);
    CM_ISSUE_W(0);

#pragma unroll 1
    for (int c = 0; c < NCH_; c++) {
        bf16x8 AF;
#pragma unroll
        for (int e = 0; e < 8; e++) AF[e] = f2bf_s(G[e >> 2][e & 3] * msk);
        if (c < NCH_-1) CM_ISSUE_G(c+1);
        acc[0] = __builtin_amdgcn_mfma_f32_16x16x32_bf16(AF, WF[0], acc[0], 0,0,0);
        acc[1] = __builtin_amdgcn_mfma_f32_16x16x32_bf16(AF, WF[1], acc[1], 0,0,0);
        if (c < NCH_-1) CM_ISSUE_W(c+1);
    }

    const int pxr = px0 + wv*16 + fq*4;
#pragma unroll
    for (int j = 0; j < 2; j++) {
        int o = j*16 + fr;
        if (o < 27) {
            float bv = cmb[o];
#pragma unroll
            for (int r = 0; r < 4; r++)
                om[(size_t)(pxr + r) * OMC_ + o] = acc[j][r] + bv;
        }
    }
}

// ---------------------------------------------------------------------------
// dcn: bf16 MFMA implicit GEMM — BARRIER-FREE / LDS-FREE.
// Lane (fr,fq) gathers its own A-fragment (px = px0+wv*16+fr, ch fq*8 and
// 32+fq*8) and bilinear-combines in registers; W-frags read straight from
// wdT in L2. 1-tap-ahead pipeline: issue G(k+1) -> om(k+2) -> MFMA(k)
// -> WF(k+1), so compiler vmcnt retires old loads without draining new.
// ---------------------------------------------------------------------------
__global__ __launch_bounds__(256, 2) void dcn_kernel(const float* __restrict__ xs,
                                                     const float* __restrict__ om,
                                                     const short* __restrict__ wdT,
                                                     const float* __restrict__ bias,
                                                     float* __restrict__ out)
{
    const int t  = threadIdx.x;
    const int wg = blockIdx.x;
    const int sw = (wg & 7) * 160 + (wg >> 3);              // XCD-contiguous
    const int px0 = sw * 64;
    const int lane = t & 63, wv = t >> 6;
    const int fr = lane & 15, fq = lane >> 4;
    const int ce = fq * 8;

    const int pxs = px0 + wv*16 + fr;
    const int wsx = pxs % W_, hs = (pxs / W_) % H_, bs = pxs / HW_;
    const float* omp = om + (size_t)pxs * OMC_;
    const size_t xrow = (size_t)bs * HW_;

    f32x4 acc[4];
#pragma unroll
    for (int j = 0; j < 4; j++) acc[j] = (f32x4){0.f,0.f,0.f,0.f};

    f4 G[16];                                               // 4 corners x 2 slices x 2
    bf16x8 WF[8];                                           // 4 o-tiles x 2 slices
    float w00, w01, w10, w11;
    float dy, dx, mz, dyn, dxn, mzn;

#define DCN_ISSUE_G(KK, DY, DX, MZ) do {                                      \
    float m_  = 1.f / (1.f + __expf(-(MZ)));                                  \
    float py_ = (float)(hs + (KK)/3 - 1) + (DY);                              \
    float px_ = (float)(wsx + (KK)%3 - 1) + (DX);                             \
    float y0f_ = floorf(py_), x0f_ = floorf(px_);                             \
    int   y0_ = (int)y0f_,   x0_ = (int)x0f_;                                 \
    float wy_ = py_ - y0f_,  wx_ = px_ - x0f_;                                \
    bool vy0_ = (y0_ >= 0)  & (y0_ < H_);                                     \
    bool vy1_ = (y0_ >= -1) & (y0_ < H_ - 1);                                 \
    bool vx0_ = (x0_ >= 0)  & (x0_ < W_);                                     \
    bool vx1_ = (x0_ >= -1) & (x0_ < W_ - 1);                                 \
    w00 = (1.f-wy_)*(1.f-wx_)*m_*((vy0_&vx0_)?1.f:0.f);                       \
    w01 = (1.f-wy_)*wx_      *m_*((vy0_&vx1_)?1.f:0.f);                       \
    w10 = wy_*(1.f-wx_)      *m_*((vy1_&vx0_)?1.f:0.f);                       \
    w11 = wy_*wx_            *m_*((vy1_&vx1_)?1.f:0.f);                       \
    int y0c_ = min(max(y0_,   0), H_-1), y1c_ = min(max(y0_+1, 0), H_-1);     \
    int x0c_ = min(max(x0_,   0), W_-1), x1c_ = min(max(x0_+1, 0), W_-1);     \
    const float* p0_ = xs + (size_t)(xrow + y0c_*W_ + x0c_)*XC_ + ce;         \
    const float* p1_ = xs + (size_t)(xrow + y0c_*W_ + x1c_)*XC_ + ce;         \
    const float* p2_ = xs + (size_t)(xrow + y1c_*W_ + x0c_)*XC_ + ce;         \
    const float* p3_ = xs + (size_t)(xrow + y1c_*W_ + x1c_)*XC_ + ce;         \
    _Pragma("unroll")                                                         \
    for (int s_ = 0; s_ < 2; s_++) {                                          \
        G[0*4+s_*2+0] = *reinterpret_cast<const f4*>(p0_ + s_*32);            \
        G[0*4+s_*2+1] = *reinterpret_cast<const f4*>(p0_ + s_*32 + 4);        \
        G[1*4+s_*2+0] = *reinterpret_cast<const f4*>(p1_ + s_*32);            \
        G[1*4+s_*2+1] = *reinterpret_cast<const f4*>(p1_ + s_*32 + 4);        \
        G[2*4+s_*2+0] = *reinterpret_cast<const f4*>(p2_ + s_*32);            \
        G[2*4+s_*2+1] = *reinterpret_cast<const f4*>(p2_ + s_*32 + 4);        \
        G[3*4+s_*2+0] = *reinterpret_cast<const f4*>(p3_ + s_*32);            \
        G[3*4+s_*2+1] = *reinterpret_cast<const f4*>(p3_ + s_*32 + 4);        \
    }                                                                         \
  } while(0)

#define DCN_ISSUE_W(KK) do {                                                  \
    const short* wp_ = wdT + (KK)*4096 + fr*64 + ce;                          \
    _Pragma("unroll")                                                         \
    for (int j_ = 0; j_ < 4; j_++) {                                          \
        WF[j_*2+0] = *reinterpret_cast<const bf16x8*>(wp_ + j_*1024);         \
        WF[j_*2+1] = *reinterpret_cast<const bf16x8*>(wp_ + j_*1024 + 32);    \
    }                                                                         \
  } while(0)

    dy = omp[0]; dx = omp[1]; mz = omp[18];
    DCN_ISSUE_G(0, dy, dx, mz);
    DCN_ISSUE_W(0);
    dyn = omp[2]; dxn = omp[3]; mzn = omp[19];

#pragma unroll 1
    for (int k = 0; k < 9; k++) {
        bf16x8 aA, aB;
#pragma unroll
        for (int e = 0; e < 8; e++) {
            int hf = e >> 2, el = e & 3;
            aA[e] = f2bf_s(w00*G[0+hf][el] + w01*G[4+hf][el]
                         + w10*G[8+hf][el] + w11*G[12+hf][el]);
        }
#pragma unroll
        for (int e = 0; e < 8; e++) {
            int hf = e >> 2, el = e & 3;
            aB[e] = f2bf_s(w00*G[2+hf][el] + w01*G[6+hf][el]
                         + w10*G[10+hf][el] + w11*G[14+hf][el]);
        }
        if (k < 8) {
            DCN_ISSUE_G(k+1, dyn, dxn, mzn);
            int kn = (k+2 < 8) ? k+2 : 8;
            dyn = omp[2*kn]; dxn = omp[2*kn+1]; mzn = omp[18+kn];
        }
#pragma unroll
        for (int j = 0; j < 4; j++) {
            acc[j] = __builtin_amdgcn_mfma_f32_16x16x32_bf16(aA, WF[j*2+0], acc[j], 0,0,0);
            acc[j] = __builtin_amdgcn_mfma_f32_16x16x32_bf16(aB, WF[j*2+1], acc[j], 0,0,0);
        }
        if (k < 8) DCN_ISSUE_W(k+1);
    }

    // ---- epilogue: D row px = wv*16 + fq*4 + reg, col o = j*16 + fr ----
    const int bo = px0 / HW_, po = px0 % HW_;
#pragma unroll
    for (int j = 0; j < 4; j++) {
        int o = j*16 + fr;
        float bv = bias[o];
        f4 r = { acc[j][0] + bv, acc[j][1] + bv, acc[j][2] + bv, acc[j][3] + bv };
        *reinterpret_cast<f4*>(&out[((size_t)(bo*64 + o))*HW_ + po + wv*16 + fq*4]) = r;
    }
}

// ---------------------------------------------------------------------------
extern "C" void kernel_launch(void* const* d_in, const int* in_sizes, int n_in,
                              void* d_out, int out_size, void* d_ws, size_t ws_size,
                              hipStream_t stream)
{
    const float* x   = (const float*)d_in[0];
    const float* wt  = (const float*)d_in[1];
    const float* bs  = (const float*)d_in[2];
    const float* cmw = (const float*)d_in[3];
    const float* cmb = (const float*)d_in[4];
    float* out = (float*)d_out;

    float* xs  = (float*)d_ws;                              // NPIX_*72 f32
    float* om  = xs + (size_t)NPIX_ * XC_;                  // NPIX_*28 f32
    short* wdT = (short*)(om + (size_t)NPIX_ * OMC_);       // 9*4096 bf16
    short* cwB = wdT + 9*4096;                              // 21*1024 bf16

    prep_kernel <<<228, 256, 0, stream>>>(wt, cmw, wdT, cwB);
    xpose_kernel<<<NPIX_/128, 128, 0, stream>>>(x, xs);
    sim_kernel  <<<NPIX_/128, 256, 0, stream>>>(xs);
    cm_kernel   <<<NPIX_/64,  256, 0, stream>>>(xs, cwB, cmb, om);
    dcn_kernel  <<<NPIX_/64,  256, 0, stream>>>(xs, om, wdT, bs, out);
}

// Round 7
// 147.080 us; speedup vs baseline: 1.0168x; 1.0168x over previous
//
#include <hip/hip_runtime.h>
#include <hip/hip_bf16.h>
#include <math.h>

#define B_    4
#define CIN_  64
#define COUT_ 64
#define H_    128
#define W_    160
#define HW_   (H_*W_)
#define NPIX_ (B_*HW_)      // 81920
#define XC_   72            // xsb channel stride: x(64) + sim(8), bf16
#define OMC_  28            // om channels padded (27 used)
#define EPS_  1e-8f
#define NCH_  21            // cm K-chunks: ceil(648/32)

typedef float  f4     __attribute__((ext_vector_type(4)));
typedef float  f32x4  __attribute__((ext_vector_type(4)));
typedef short  bf16x8 __attribute__((ext_vector_type(8)));
typedef short  bf16x4 __attribute__((ext_vector_type(4)));

static __device__ __forceinline__ short f2bf_s(float f) {
    __hip_bfloat16 h = __float2bfloat16(f);
    return *reinterpret_cast<short*>(&h);
}
static __device__ __forceinline__ float b2f(short s) {
    union { unsigned u; float f; } cv;
    cv.u = ((unsigned)(unsigned short)s) << 16;
    return cv.f;
}

// ---------------------------------------------------------------------------
// prep:
//  wdT[k][o][c] bf16 (9*64*64): plain-layout dcn weights (read from L2).
//  cwB[ch][o][kk] bf16 (21*32*32): cm weights per K-chunk, zero-padded.
// ---------------------------------------------------------------------------
__global__ __launch_bounds__(256) void prep_kernel(const float* __restrict__ wt,
                                                   const float* __restrict__ cmw,
                                                   short* __restrict__ wdT,
                                                   short* __restrict__ cwB)
{
    int i = blockIdx.x * 256 + threadIdx.x;
    if (i < 9*4096) {
        int k = i >> 12, r = i & 4095, o = r >> 6, c = r & 63;
        wdT[i] = f2bf_s(wt[(o*64 + c)*9 + k]);
    }
    int j = i - 9*4096;
    if (j >= 0 && j < NCH_*1024) {
        int cch = j >> 10, r = j & 1023, o = r >> 5, kk = r & 31;
        int k = cch*32 + kk;
        short v = 0;
        if (o < 27 && k < 648) {
            int tap = k / 72, ch = k - (k/72)*72;
            v = f2bf_s(cmw[((size_t)o*72 + ch)*9 + tap]);
        }
        cwB[j] = v;
    }
}

// ---------------------------------------------------------------------------
// xpose: NCHW f32 x -> bf16 NHWC xsb[px][0..63] (ch 64..71 filled by sim).
// ---------------------------------------------------------------------------
__global__ __launch_bounds__(128) void xpose_kernel(const float* __restrict__ x,
                                                    short* __restrict__ xsb)
{
    __shared__ float l[128][65];
    const int t = threadIdx.x;
    const int px0 = blockIdx.x * 128;
    const int b = px0 / HW_, p0 = px0 % HW_;
    for (int c = 0; c < 64; c++)
        l[t][c] = x[((size_t)(b*64 + c))*HW_ + p0 + t];
    __syncthreads();
#pragma unroll
    for (int rep = 0; rep < 16; rep++) {
        int pxl = (t >> 4) + rep*8;
        int c4  = (t & 15) * 4;
        bf16x4 v = { f2bf_s(l[pxl][c4]),   f2bf_s(l[pxl][c4+1]),
                     f2bf_s(l[pxl][c4+2]), f2bf_s(l[pxl][c4+3]) };
        *reinterpret_cast<bf16x4*>(&xsb[(size_t)(px0+pxl)*XC_ + c4]) = v;
    }
}

// ---------------------------------------------------------------------------
// sim: 2 threads/pixel (channel halves), shfl_xor(1) combine, bf16 reads.
// Writes xsb[px][64+n]. Grid 640.
// ---------------------------------------------------------------------------
__global__ __launch_bounds__(256, 4) void sim_kernel(short* __restrict__ xsb)
{
    const int t = threadIdx.x;
    const int wg = blockIdx.x;
    const int sw = (wg & 7) * 80 + (wg >> 3);               // XCD-contiguous
    const int px = sw * 128 + (t >> 1);
    const int h = t & 1;
    const int w = px % W_, hh = (px / W_) % H_, b = px / HW_;

    const short* cen = xsb + (size_t)px * XC_ + h*32;
    float cv[32]; float ncc = 0.f;
#pragma unroll
    for (int q = 0; q < 4; q++) {
        bf16x8 cb = *reinterpret_cast<const bf16x8*>(cen + q*8);
#pragma unroll
        for (int j = 0; j < 8; j++) {
            float v = b2f(cb[j]);
            cv[q*8+j] = v;
            ncc = fmaf(v, v, ncc);
        }
    }

    const int kyA[8] = {-1,-1,-1, 0, 0, 1, 1, 1};
    const int kxA[8] = {-1, 0, 1,-1, 1,-1, 0, 1};
    float dot[8], nn[8];
#pragma unroll
    for (int n = 0; n < 8; n++) {
        int hn = hh + kyA[n], wn = w + kxA[n];
        bool v = (hn >= 0) & (hn < H_) & (wn >= 0) & (wn < W_);
        float msk = v ? 1.f : 0.f;
        const short* nb = xsb + (size_t)(b*HW_ + min(max(hn,0),H_-1)*W_ + min(max(wn,0),W_-1))*XC_ + h*32;
        float d = 0.f, s2 = 0.f;
#pragma unroll
        for (int q = 0; q < 4; q++) {
            bf16x8 qb = *reinterpret_cast<const bf16x8*>(nb + q*8);
#pragma unroll
            for (int j = 0; j < 8; j++) {
                float vv = b2f(qb[j]) * msk;
                d  = fmaf(cv[q*8+j], vv, d);
                s2 = fmaf(vv, vv, s2);
            }
        }
        dot[n] = d; nn[n] = s2;
    }
    ncc += __shfl_xor(ncc, 1);
    const float ncr = 1.f / fmaxf(sqrtf(ncc), EPS_);
    float res[8];
#pragma unroll
    for (int n = 0; n < 8; n++) {
        float dt = dot[n] + __shfl_xor(dot[n], 1);
        float s2 = nn[n]  + __shfl_xor(nn[n], 1);
        res[n] = dt * ncr / fmaxf(sqrtf(s2), EPS_);
    }
    bf16x4 r = { f2bf_s(h ? res[4] : res[0]), f2bf_s(h ? res[5] : res[1]),
                 f2bf_s(h ? res[6] : res[2]), f2bf_s(h ? res[7] : res[3]) };
    *reinterpret_cast<bf16x4*>(xsb + (size_t)px * XC_ + 64 + h*4) = r;
}

// ---------------------------------------------------------------------------
// cm: 3x3 conv 72->27 as bf16 MFMA implicit GEMM — barrier-free / LDS-free.
// Lane (fr,fq) gathers its own A-fragment: ONE bf16x8 load + exact binary
// masking via select (no cvt). W-frags straight from cwB in L2. 1-chunk
// lookahead in loop-carried regs (small: 4+8 VGPR).
// ---------------------------------------------------------------------------
__global__ __launch_bounds__(256, 4) void cm_kernel(const short* __restrict__ xsb,
                                                    const short* __restrict__ cwB,
                                                    const float* __restrict__ cmb,
                                                    float* __restrict__ om)
{
    const int t  = threadIdx.x;
    const int wg = blockIdx.x;
    const int sw = (wg & 7) * 160 + (wg >> 3);              // XCD-contiguous
    const int px0 = sw * 64;
    const int lane = t & 63, wv = t >> 6;
    const int fr = lane & 15, fq = lane >> 4;

    const int pxs = px0 + wv*16 + fr;
    const int wsx = pxs % W_, hs = (pxs / W_) % H_, bs = pxs / HW_;
    const size_t xrow = (size_t)bs * HW_;

    f32x4 acc[2];
    acc[0] = (f32x4){0.f,0.f,0.f,0.f};
    acc[1] = (f32x4){0.f,0.f,0.f,0.f};

    bf16x8 G8; bf16x8 WF[2]; bool mskb;

#define CM_ISSUE_G(CH) do {                                                   \
    int k0_ = (CH)*32 + fq*8;                                                 \
    int tap_ = (k0_ * 911) >> 16;                                             \
    bool valid_ = (tap_ < 9);                                                 \
    tap_ = min(tap_, 8);                                                      \
    int ch_ = min(max(k0_ - tap_*72, 0), 64);                                 \
    int t3_ = (tap_ * 11) >> 5;                                               \
    int hy_ = hs + t3_ - 1, wx_ = wsx + (tap_ - t3_*3) - 1;                   \
    bool v_ = (hy_ >= 0) & (hy_ < H_) & (wx_ >= 0) & (wx_ < W_);              \
    mskb = v_ & valid_;                                                       \
    const short* src_ = xsb + (size_t)(xrow + min(max(hy_,0),H_-1)*W_         \
                                       + min(max(wx_,0),W_-1))*XC_ + ch_;     \
    G8 = *reinterpret_cast<const bf16x8*>(src_);                              \
  } while(0)

#define CM_ISSUE_W(CH) do {                                                   \
    const short* wp_ = cwB + (CH)*1024 + fr*32 + fq*8;                        \
    WF[0] = *reinterpret_cast<const bf16x8*>(wp_);                            \
    WF[1] = *reinterpret_cast<const bf16x8*>(wp_ + 512);                      \
  } while(0)

    CM_ISSUE_G(0);
    CM_ISSUE_W(0);

#pragma unroll 1
    for (int c = 0; c < NCH_; c++) {
        bf16x8 zero8 = {0,0,0,0,0,0,0,0};
        bf16x8 AF = mskb ? G8 : zero8;                      // exact binary mask
        bf16x8 W0 = WF[0], W1 = WF[1];
        if (c < NCH_-1) { CM_ISSUE_G(c+1); CM_ISSUE_W(c+1); }
        acc[0] = __builtin_amdgcn_mfma_f32_16x16x32_bf16(AF, W0, acc[0], 0,0,0);
        acc[1] = __builtin_amdgcn_mfma_f32_16x16x32_bf16(AF, W1, acc[1], 0,0,0);
    }

    const int pxr = px0 + wv*16 + fq*4;
#pragma unroll
    for (int j = 0; j < 2; j++) {
        int o = j*16 + fr;
        if (o < 27) {
            float bv = cmb[o];
#pragma unroll
            for (int r = 0; r < 4; r++)
                om[(size_t)(pxr + r) * OMC_ + o] = acc[j][r] + bv;
        }
    }
}

// ---------------------------------------------------------------------------
// dcn: bf16 MFMA implicit GEMM — barrier-free / LDS-free, occupancy-first.
// Lane (fr,fq) gathers its own A-fragment as bf16 (8 x 16B loads = 32 VGPR
// in flight), combines bilinear in f32, no cross-tap G prefetch (waves hide
// latency). W-frags straight from wdT in L2.
// ---------------------------------------------------------------------------
__global__ __launch_bounds__(256, 4) void dcn_kernel(const short* __restrict__ xsb,
                                                     const float* __restrict__ om,
                                                     const short* __restrict__ wdT,
                                                     const float* __restrict__ bias,
                                                     float* __restrict__ out)
{
    const int t  = threadIdx.x;
    const int wg = blockIdx.x;
    const int sw = (wg & 7) * 160 + (wg >> 3);              // XCD-contiguous
    const int px0 = sw * 64;
    const int lane = t & 63, wv = t >> 6;
    const int fr = lane & 15, fq = lane >> 4;
    const int ce = fq * 8;

    const int pxs = px0 + wv*16 + fr;
    const int wsx = pxs % W_, hs = (pxs / W_) % H_, bs = pxs / HW_;
    const float* omp = om + (size_t)pxs * OMC_;
    const size_t xrow = (size_t)bs * HW_;

    f32x4 acc[4];
#pragma unroll
    for (int j = 0; j < 4; j++) acc[j] = (f32x4){0.f,0.f,0.f,0.f};

    float dy = omp[0], dx = omp[1], mz = omp[18];

#pragma unroll 1
    for (int k = 0; k < 9; k++) {
        // ---- bilinear meta ----
        float m_  = 1.f / (1.f + __expf(-mz));
        float py_ = (float)(hs + k/3 - 1) + dy;
        float px_ = (float)(wsx + k%3 - 1) + dx;
        float y0f = floorf(py_), x0f = floorf(px_);
        int   y0 = (int)y0f,   x0 = (int)x0f;
        float wy = py_ - y0f,  wx = px_ - x0f;
        bool vy0 = (y0 >= 0)  & (y0 < H_);
        bool vy1 = (y0 >= -1) & (y0 < H_ - 1);
        bool vx0 = (x0 >= 0)  & (x0 < W_);
        bool vx1 = (x0 >= -1) & (x0 < W_ - 1);
        float w00 = (1.f-wy)*(1.f-wx)*m_*((vy0&vx0)?1.f:0.f);
        float w01 = (1.f-wy)*wx      *m_*((vy0&vx1)?1.f:0.f);
        float w10 = wy*(1.f-wx)      *m_*((vy1&vx0)?1.f:0.f);
        float w11 = wy*wx            *m_*((vy1&vx1)?1.f:0.f);
        int y0c = min(max(y0,   0), H_-1), y1c = min(max(y0+1, 0), H_-1);
        int x0c = min(max(x0,   0), W_-1), x1c = min(max(x0+1, 0), W_-1);
        const short* p0_ = xsb + (size_t)(xrow + y0c*W_ + x0c)*XC_ + ce;
        const short* p1_ = xsb + (size_t)(xrow + y0c*W_ + x1c)*XC_ + ce;
        const short* p2_ = xsb + (size_t)(xrow + y1c*W_ + x0c)*XC_ + ce;
        const short* p3_ = xsb + (size_t)(xrow + y1c*W_ + x1c)*XC_ + ce;

        // ---- issue 8 bf16 gathers (2 k-slices x 4 corners) ----
        bf16x8 G[8];
        G[0] = *reinterpret_cast<const bf16x8*>(p0_);
        G[1] = *reinterpret_cast<const bf16x8*>(p0_ + 32);
        G[2] = *reinterpret_cast<const bf16x8*>(p1_);
        G[3] = *reinterpret_cast<const bf16x8*>(p1_ + 32);
        G[4] = *reinterpret_cast<const bf16x8*>(p2_);
        G[5] = *reinterpret_cast<const bf16x8*>(p2_ + 32);
        G[6] = *reinterpret_cast<const bf16x8*>(p3_);
        G[7] = *reinterpret_cast<const bf16x8*>(p3_ + 32);

        // ---- W fragments from L2 ----
        bf16x8 WF[8];
        const short* wp_ = wdT + k*4096 + fr*64 + ce;
#pragma unroll
        for (int j = 0; j < 4; j++) {
            WF[j*2+0] = *reinterpret_cast<const bf16x8*>(wp_ + j*1024);
            WF[j*2+1] = *reinterpret_cast<const bf16x8*>(wp_ + j*1024 + 32);
        }

        // ---- next tap's offsets (cheap, L1-hot) ----
        float dyn = 0.f, dxn = 0.f, mzn = 0.f;
        if (k < 8) { dyn = omp[2*k+2]; dxn = omp[2*k+3]; mzn = omp[19+k]; }

        // ---- combine in f32, round to bf16 ----
        bf16x8 aA, aB;
#pragma unroll
        for (int e = 0; e < 8; e++)
            aA[e] = f2bf_s(w00*b2f(G[0][e]) + w01*b2f(G[2][e])
                         + w10*b2f(G[4][e]) + w11*b2f(G[6][e]));
#pragma unroll
        for (int e = 0; e < 8; e++)
            aB[e] = f2bf_s(w00*b2f(G[1][e]) + w01*b2f(G[3][e])
                         + w10*b2f(G[5][e]) + w11*b2f(G[7][e]));

#pragma unroll
        for (int j = 0; j < 4; j++) {
            acc[j] = __builtin_amdgcn_mfma_f32_16x16x32_bf16(aA, WF[j*2+0], acc[j], 0,0,0);
            acc[j] = __builtin_amdgcn_mfma_f32_16x16x32_bf16(aB, WF[j*2+1], acc[j], 0,0,0);
        }
        dy = dyn; dx = dxn; mz = mzn;
    }

    // ---- epilogue: D row px = wv*16 + fq*4 + reg, col o = j*16 + fr ----
    const int bo = px0 / HW_, po = px0 % HW_;
#pragma unroll
    for (int j = 0; j < 4; j++) {
        int o = j*16 + fr;
        float bv = bias[o];
        f4 r = { acc[j][0] + bv, acc[j][1] + bv, acc[j][2] + bv, acc[j][3] + bv };
        *reinterpret_cast<f4*>(&out[((size_t)(bo*64 + o))*HW_ + po + wv*16 + fq*4]) = r;
    }
}

// ---------------------------------------------------------------------------
extern "C" void kernel_launch(void* const* d_in, const int* in_sizes, int n_in,
                              void* d_out, int out_size, void* d_ws, size_t ws_size,
                              hipStream_t stream)
{
    const float* x   = (const float*)d_in[0];
    const float* wt  = (const float*)d_in[1];
    const float* bs  = (const float*)d_in[2];
    const float* cmw = (const float*)d_in[3];
    const float* cmb = (const float*)d_in[4];
    float* out = (float*)d_out;

    float* om  = (float*)d_ws;                              // NPIX_*28 f32
    short* xsb = (short*)(om + (size_t)NPIX_ * OMC_);       // NPIX_*72 bf16
    short* wdT = xsb + (size_t)NPIX_ * XC_;                 // 9*4096 bf16
    short* cwB = wdT + 9*4096;                              // 21*1024 bf16

    prep_kernel <<<228, 256, 0, stream>>>(wt, cmw, wdT, cwB);
    xpose_kernel<<<NPIX_/128, 128, 0, stream>>>(x, xsb);
    sim_kernel  <<<NPIX_/128, 256, 0, stream>>>(xsb);
    cm_kernel   <<<NPIX_/64,  256, 0, stream>>>(xsb, cwB, cmb, om);
    dcn_kernel  <<<NPIX_/64,  256, 0, stream>>>(xsb, om, wdT, bs, out);
}

// Round 8
// 141.004 us; speedup vs baseline: 1.0606x; 1.0431x over previous
//
#include <hip/hip_runtime.h>
#include <hip/hip_bf16.h>
#include <math.h>

#define B_    4
#define CIN_  64
#define COUT_ 64
#define H_    128
#define W_    160
#define HW_   (H_*W_)
#define NPIX_ (B_*HW_)      // 81920
#define XC_   72            // xsb channel stride: x(64) + sim(8), bf16
#define OMC_  28            // om channels padded (27 used)
#define EPS_  1e-8f
#define NCH_  21            // cm K-chunks: ceil(648/32)

typedef float  f4     __attribute__((ext_vector_type(4)));
typedef float  f32x4  __attribute__((ext_vector_type(4)));
typedef short  bf16x8 __attribute__((ext_vector_type(8)));
typedef short  bf16x4 __attribute__((ext_vector_type(4)));

static __device__ __forceinline__ short f2bf_s(float f) {
    __hip_bfloat16 h = __float2bfloat16(f);
    return *reinterpret_cast<short*>(&h);
}
static __device__ __forceinline__ float b2f(short s) {
    union { unsigned u; float f; } cv;
    cv.u = ((unsigned)(unsigned short)s) << 16;
    return cv.f;
}

// ---------------------------------------------------------------------------
// prep:
//  wdT[k][o][c] bf16 (9*64*64): plain-layout dcn weights (read from L2).
//  cwB[ch][o][kk] bf16 (21*32*32): cm weights per K-chunk, zero-padded.
// ---------------------------------------------------------------------------
__global__ __launch_bounds__(256) void prep_kernel(const float* __restrict__ wt,
                                                   const float* __restrict__ cmw,
                                                   short* __restrict__ wdT,
                                                   short* __restrict__ cwB)
{
    int i = blockIdx.x * 256 + threadIdx.x;
    if (i < 9*4096) {
        int k = i >> 12, r = i & 4095, o = r >> 6, c = r & 63;
        wdT[i] = f2bf_s(wt[(o*64 + c)*9 + k]);
    }
    int j = i - 9*4096;
    if (j >= 0 && j < NCH_*1024) {
        int cch = j >> 10, r = j & 1023, o = r >> 5, kk = r & 31;
        int k = cch*32 + kk;
        short v = 0;
        if (o < 27 && k < 648) {
            int tap = k / 72, ch = k - (k/72)*72;
            v = f2bf_s(cmw[((size_t)o*72 + ch)*9 + tap]);
        }
        cwB[j] = v;
    }
}

// ---------------------------------------------------------------------------
// xpose: NCHW f32 x -> bf16 NHWC xsb[px][0..63] (ch 64..71 filled by sim).
// ---------------------------------------------------------------------------
__global__ __launch_bounds__(128) void xpose_kernel(const float* __restrict__ x,
                                                    short* __restrict__ xsb)
{
    __shared__ float l[128][65];
    const int t = threadIdx.x;
    const int px0 = blockIdx.x * 128;
    const int b = px0 / HW_, p0 = px0 % HW_;
    for (int c = 0; c < 64; c++)
        l[t][c] = x[((size_t)(b*64 + c))*HW_ + p0 + t];
    __syncthreads();
#pragma unroll
    for (int rep = 0; rep < 16; rep++) {
        int pxl = (t >> 4) + rep*8;
        int c4  = (t & 15) * 4;
        bf16x4 v = { f2bf_s(l[pxl][c4]),   f2bf_s(l[pxl][c4+1]),
                     f2bf_s(l[pxl][c4+2]), f2bf_s(l[pxl][c4+3]) };
        *reinterpret_cast<bf16x4*>(&xsb[(size_t)(px0+pxl)*XC_ + c4]) = v;
    }
}

// ---------------------------------------------------------------------------
// sim: 4 threads/pixel (16-ch quarters), 2-level shfl_xor combine.
// 64-thread blocks, 16 px each, grid 5120. Writes xsb[px][64..71].
// ---------------------------------------------------------------------------
__global__ __launch_bounds__(64, 5) void sim_kernel(short* __restrict__ xsb)
{
    const int t = threadIdx.x;
    const int wg = blockIdx.x;
    const int sw = (wg & 7) * 640 + (wg >> 3);              // XCD-contiguous
    const int px = sw * 16 + (t >> 2);
    const int q = t & 3;
    const int w = px % W_, hh = (px / W_) % H_, b = px / HW_;

    const short* cen = xsb + (size_t)px * XC_ + q*16;
    float cv[16]; float ncc = 0.f;
#pragma unroll
    for (int s = 0; s < 2; s++) {
        bf16x8 cb = *reinterpret_cast<const bf16x8*>(cen + s*8);
#pragma unroll
        for (int j = 0; j < 8; j++) {
            float v = b2f(cb[j]);
            cv[s*8+j] = v;
            ncc = fmaf(v, v, ncc);
        }
    }

    const int kyA[8] = {-1,-1,-1, 0, 0, 1, 1, 1};
    const int kxA[8] = {-1, 0, 1,-1, 1,-1, 0, 1};
    float dot[8], nn[8];
#pragma unroll
    for (int n = 0; n < 8; n++) {
        int hn = hh + kyA[n], wn = w + kxA[n];
        bool v = (hn >= 0) & (hn < H_) & (wn >= 0) & (wn < W_);
        float msk = v ? 1.f : 0.f;
        const short* nb = xsb + (size_t)(b*HW_ + min(max(hn,0),H_-1)*W_ + min(max(wn,0),W_-1))*XC_ + q*16;
        float d = 0.f, s2 = 0.f;
#pragma unroll
        for (int s = 0; s < 2; s++) {
            bf16x8 qb = *reinterpret_cast<const bf16x8*>(nb + s*8);
#pragma unroll
            for (int j = 0; j < 8; j++) {
                float vv = b2f(qb[j]) * msk;
                d  = fmaf(cv[s*8+j], vv, d);
                s2 = fmaf(vv, vv, s2);
            }
        }
        dot[n] = d; nn[n] = s2;
    }
    // 4-lane group reduce
    ncc += __shfl_xor(ncc, 1); ncc += __shfl_xor(ncc, 2);
    const float ncr = 1.f / fmaxf(sqrtf(ncc), EPS_);
    float res[8];
#pragma unroll
    for (int n = 0; n < 8; n++) {
        float dt = dot[n]; dt += __shfl_xor(dt, 1); dt += __shfl_xor(dt, 2);
        float s2 = nn[n];  s2 += __shfl_xor(s2, 1); s2 += __shfl_xor(s2, 2);
        res[n] = dt * ncr / fmaxf(sqrtf(s2), EPS_);
    }
    if (q < 2) {
        bf16x4 r = { f2bf_s(res[q*4]),   f2bf_s(res[q*4+1]),
                     f2bf_s(res[q*4+2]), f2bf_s(res[q*4+3]) };
        *reinterpret_cast<bf16x4*>(xsb + (size_t)px * XC_ + 64 + q*4) = r;
    }
}

// ---------------------------------------------------------------------------
// cm: 3x3 conv 72->27 as bf16 MFMA implicit GEMM — barrier-free / LDS-free.
// 128-thread blocks (2 waves x 16px x 32o), grid 2560.
// ---------------------------------------------------------------------------
__global__ __launch_bounds__(128, 5) void cm_kernel(const short* __restrict__ xsb,
                                                    const short* __restrict__ cwB,
                                                    const float* __restrict__ cmb,
                                                    float* __restrict__ om)
{
    const int t  = threadIdx.x;
    const int wg = blockIdx.x;
    const int sw = (wg & 7) * 320 + (wg >> 3);              // XCD-contiguous
    const int px0 = sw * 32;
    const int lane = t & 63, wv = t >> 6;
    const int fr = lane & 15, fq = lane >> 4;

    const int pxs = px0 + wv*16 + fr;
    const int wsx = pxs % W_, hs = (pxs / W_) % H_, bs = pxs / HW_;
    const size_t xrow = (size_t)bs * HW_;

    f32x4 acc[2];
    acc[0] = (f32x4){0.f,0.f,0.f,0.f};
    acc[1] = (f32x4){0.f,0.f,0.f,0.f};

    bf16x8 G8; bf16x8 WF[2]; bool mskb;

#define CM_ISSUE_G(CH) do {                                                   \
    int k0_ = (CH)*32 + fq*8;                                                 \
    int tap_ = (k0_ * 911) >> 16;                                             \
    bool valid_ = (tap_ < 9);                                                 \
    tap_ = min(tap_, 8);                                                      \
    int ch_ = min(max(k0_ - tap_*72, 0), 64);                                 \
    int t3_ = (tap_ * 11) >> 5;                                               \
    int hy_ = hs + t3_ - 1, wx_ = wsx + (tap_ - t3_*3) - 1;                   \
    bool v_ = (hy_ >= 0) & (hy_ < H_) & (wx_ >= 0) & (wx_ < W_);              \
    mskb = v_ & valid_;                                                       \
    const short* src_ = xsb + (size_t)(xrow + min(max(hy_,0),H_-1)*W_         \
                                       + min(max(wx_,0),W_-1))*XC_ + ch_;     \
    G8 = *reinterpret_cast<const bf16x8*>(src_);                              \
  } while(0)

#define CM_ISSUE_W(CH) do {                                                   \
    const short* wp_ = cwB + (CH)*1024 + fr*32 + fq*8;                        \
    WF[0] = *reinterpret_cast<const bf16x8*>(wp_);                            \
    WF[1] = *reinterpret_cast<const bf16x8*>(wp_ + 512);                      \
  } while(0)

    CM_ISSUE_G(0);
    CM_ISSUE_W(0);

#pragma unroll 1
    for (int c = 0; c < NCH_; c++) {
        bf16x8 zero8 = {0,0,0,0,0,0,0,0};
        bf16x8 AF = mskb ? G8 : zero8;                      // exact binary mask
        bf16x8 W0 = WF[0], W1 = WF[1];
        if (c < NCH_-1) { CM_ISSUE_G(c+1); CM_ISSUE_W(c+1); }
        acc[0] = __builtin_amdgcn_mfma_f32_16x16x32_bf16(AF, W0, acc[0], 0,0,0);
        acc[1] = __builtin_amdgcn_mfma_f32_16x16x32_bf16(AF, W1, acc[1], 0,0,0);
    }

    const int pxr = px0 + wv*16 + fq*4;
#pragma unroll
    for (int j = 0; j < 2; j++) {
        int o = j*16 + fr;
        if (o < 27) {
            float bv = cmb[o];
#pragma unroll
            for (int r = 0; r < 4; r++)
                om[(size_t)(pxr + r) * OMC_ + o] = acc[j][r] + bv;
        }
    }
}

// ---------------------------------------------------------------------------
// dcn: bf16 MFMA implicit GEMM — barrier-free / LDS-free, occupancy-first.
// 128-thread blocks (2 waves x 16px x 64o), grid 2560. Meta-only 1-tap
// software pipeline: bilinear weights+pointers for k+1 computed under the
// gather-k latency (~12 loop-carried VGPR, unlike R6's 64-VGPR G prefetch).
// ---------------------------------------------------------------------------
__global__ __launch_bounds__(128, 5) void dcn_kernel(const short* __restrict__ xsb,
                                                     const float* __restrict__ om,
                                                     const short* __restrict__ wdT,
                                                     const float* __restrict__ bias,
                                                     float* __restrict__ out)
{
    const int t  = threadIdx.x;
    const int wg = blockIdx.x;
    const int sw = (wg & 7) * 320 + (wg >> 3);              // XCD-contiguous
    const int px0 = sw * 32;
    const int lane = t & 63, wv = t >> 6;
    const int fr = lane & 15, fq = lane >> 4;
    const int ce = fq * 8;

    const int pxs = px0 + wv*16 + fr;
    const int wsx = pxs % W_, hs = (pxs / W_) % H_, bs = pxs / HW_;
    const float* omp = om + (size_t)pxs * OMC_;
    const size_t xrow = (size_t)bs * HW_;

    f32x4 acc[4];
#pragma unroll
    for (int j = 0; j < 4; j++) acc[j] = (f32x4){0.f,0.f,0.f,0.f};

    float w00, w01, w10, w11;
    const short *p0, *p1, *p2, *p3;

#define DCN_META(KK, DY, DX, MZ, W00, W01, W10, W11, P0, P1, P2, P3) do {     \
    float m_  = 1.f / (1.f + __expf(-(MZ)));                                  \
    float py_ = (float)(hs + (KK)/3 - 1) + (DY);                              \
    float px_ = (float)(wsx + (KK)%3 - 1) + (DX);                             \
    float y0f_ = floorf(py_), x0f_ = floorf(px_);                             \
    int   y0_ = (int)y0f_,   x0_ = (int)x0f_;                                 \
    float wy_ = py_ - y0f_,  wx_ = px_ - x0f_;                                \
    bool vy0_ = (y0_ >= 0)  & (y0_ < H_);                                     \
    bool vy1_ = (y0_ >= -1) & (y0_ < H_ - 1);                                 \
    bool vx0_ = (x0_ >= 0)  & (x0_ < W_);                                     \
    bool vx1_ = (x0_ >= -1) & (x0_ < W_ - 1);                                 \
    W00 = (1.f-wy_)*(1.f-wx_)*m_*((vy0_&vx0_)?1.f:0.f);                       \
    W01 = (1.f-wy_)*wx_      *m_*((vy0_&vx1_)?1.f:0.f);                       \
    W10 = wy_*(1.f-wx_)      *m_*((vy1_&vx0_)?1.f:0.f);                       \
    W11 = wy_*wx_            *m_*((vy1_&vx1_)?1.f:0.f);                       \
    int y0c_ = min(max(y0_,   0), H_-1), y1c_ = min(max(y0_+1, 0), H_-1);     \
    int x0c_ = min(max(x0_,   0), W_-1), x1c_ = min(max(x0_+1, 0), W_-1);     \
    P0 = xsb + (size_t)(xrow + y0c_*W_ + x0c_)*XC_ + ce;                      \
    P1 = xsb + (size_t)(xrow + y0c_*W_ + x1c_)*XC_ + ce;                      \
    P2 = xsb + (size_t)(xrow + y1c_*W_ + x0c_)*XC_ + ce;                      \
    P3 = xsb + (size_t)(xrow + y1c_*W_ + x1c_)*XC_ + ce;                      \
  } while(0)

    {
        float dy0 = omp[0], dx0 = omp[1], mz0 = omp[18];
        DCN_META(0, dy0, dx0, mz0, w00, w01, w10, w11, p0, p1, p2, p3);
    }

#pragma unroll 1
    for (int k = 0; k < 9; k++) {
        // ---- issue 8 bf16 gathers for tap k (oldest in vmcnt order) ----
        bf16x8 G[8];
        G[0] = *reinterpret_cast<const bf16x8*>(p0);
        G[1] = *reinterpret_cast<const bf16x8*>(p0 + 32);
        G[2] = *reinterpret_cast<const bf16x8*>(p1);
        G[3] = *reinterpret_cast<const bf16x8*>(p1 + 32);
        G[4] = *reinterpret_cast<const bf16x8*>(p2);
        G[5] = *reinterpret_cast<const bf16x8*>(p2 + 32);
        G[6] = *reinterpret_cast<const bf16x8*>(p3);
        G[7] = *reinterpret_cast<const bf16x8*>(p3 + 32);

        // ---- W fragments from L2 ----
        bf16x8 WF[8];
        const short* wp_ = wdT + k*4096 + fr*64 + ce;
#pragma unroll
        for (int j = 0; j < 4; j++) {
            WF[j*2+0] = *reinterpret_cast<const bf16x8*>(wp_ + j*1024);
            WF[j*2+1] = *reinterpret_cast<const bf16x8*>(wp_ + j*1024 + 32);
        }

        // ---- meta(k+1): independent of G -> runs under gather latency ----
        float n00 = w00, n01 = w01, n10 = w10, n11 = w11;
        const short *q0 = p0, *q1 = p1, *q2 = p2, *q3 = p3;
        if (k < 8) {
            float dyn = omp[2*k+2], dxn = omp[2*k+3], mzn = omp[19+k];
            DCN_META(k+1, dyn, dxn, mzn, n00, n01, n10, n11, q0, q1, q2, q3);
        }

        // ---- combine in f32, round to bf16 (waits on G) ----
        bf16x8 aA, aB;
#pragma unroll
        for (int e = 0; e < 8; e++)
            aA[e] = f2bf_s(w00*b2f(G[0][e]) + w01*b2f(G[2][e])
                         + w10*b2f(G[4][e]) + w11*b2f(G[6][e]));
#pragma unroll
        for (int e = 0; e < 8; e++)
            aB[e] = f2bf_s(w00*b2f(G[1][e]) + w01*b2f(G[3][e])
                         + w10*b2f(G[5][e]) + w11*b2f(G[7][e]));

#pragma unroll
        for (int j = 0; j < 4; j++) {
            acc[j] = __builtin_amdgcn_mfma_f32_16x16x32_bf16(aA, WF[j*2+0], acc[j], 0,0,0);
            acc[j] = __builtin_amdgcn_mfma_f32_16x16x32_bf16(aB, WF[j*2+1], acc[j], 0,0,0);
        }
        w00 = n00; w01 = n01; w10 = n10; w11 = n11;
        p0 = q0; p1 = q1; p2 = q2; p3 = q3;
    }

    // ---- epilogue: D row px = wv*16 + fq*4 + reg, col o = j*16 + fr ----
    const int bo = px0 / HW_, po = px0 % HW_;
#pragma unroll
    for (int j = 0; j < 4; j++) {
        int o = j*16 + fr;
        float bv = bias[o];
        f4 r = { acc[j][0] + bv, acc[j][1] + bv, acc[j][2] + bv, acc[j][3] + bv };
        *reinterpret_cast<f4*>(&out[((size_t)(bo*64 + o))*HW_ + po + wv*16 + fq*4]) = r;
    }
}

// ---------------------------------------------------------------------------
extern "C" void kernel_launch(void* const* d_in, const int* in_sizes, int n_in,
                              void* d_out, int out_size, void* d_ws, size_t ws_size,
                              hipStream_t stream)
{
    const float* x   = (const float*)d_in[0];
    const float* wt  = (const float*)d_in[1];
    const float* bs  = (const float*)d_in[2];
    const float* cmw = (const float*)d_in[3];
    const float* cmb = (const float*)d_in[4];
    float* out = (float*)d_out;

    float* om  = (float*)d_ws;                              // NPIX_*28 f32
    short* xsb = (short*)(om + (size_t)NPIX_ * OMC_);       // NPIX_*72 bf16
    short* wdT = xsb + (size_t)NPIX_ * XC_;                 // 9*4096 bf16
    short* cwB = wdT + 9*4096;                              // 21*1024 bf16

    prep_kernel <<<228, 256, 0, stream>>>(wt, cmw, wdT, cwB);
    xpose_kernel<<<NPIX_/128, 128, 0, stream>>>(x, xsb);
    sim_kernel  <<<NPIX_/16,  64,  0, stream>>>(xsb);
    cm_kernel   <<<NPIX_/32,  128, 0, stream>>>(xsb, cwB, cmb, om);
    dcn_kernel  <<<NPIX_/32,  128, 0, stream>>>(xsb, om, wdT, bs, out);
}

// Round 9
// 102.169 us; speedup vs baseline: 1.4638x; 1.3801x over previous
//
#include <hip/hip_runtime.h>
#include <hip/hip_bf16.h>
#include <math.h>

#define B_    4
#define CIN_  64
#define COUT_ 64
#define H_    128
#define W_    160
#define HW_   (H_*W_)
#define NPIX_ (B_*HW_)      // 81920
#define XC_   72            // xsb channel stride: x(64) + sim(8), bf16
#define OMC_  28            // om channels padded (27 used)
#define EPS_  1e-8f
#define NCH_  21            // cm K-chunks: ceil(648/32)

typedef float  f4     __attribute__((ext_vector_type(4)));
typedef float  f32x4  __attribute__((ext_vector_type(4)));
typedef short  bf16x8 __attribute__((ext_vector_type(8)));
typedef short  bf16x4 __attribute__((ext_vector_type(4)));

static __device__ __forceinline__ short f2bf_s(float f) {
    __hip_bfloat16 h = __float2bfloat16(f);
    return *reinterpret_cast<short*>(&h);
}
static __device__ __forceinline__ float b2f(short s) {
    union { unsigned u; float f; } cv;
    cv.u = ((unsigned)(unsigned short)s) << 16;
    return cv.f;
}

// ---------------------------------------------------------------------------
// prep:
//  wlin[k][j][s][lane][8] bf16 (9*4096): dcn W-fragments PRE-LINEARIZED so a
//    wave reads each (j,s) fragment as ONE coalesced 1KB load at lane*16B.
//    element: o = j*16+(lane&15), c = s*32+(lane>>4)*8+e.
//  cwL[CH][s][lane][8] bf16 (21*1024): cm W-fragments, same linearization.
//    element: o = s*16+(lane&15), k = CH*32+(lane>>4)*8+e (zero-padded).
// ---------------------------------------------------------------------------
__global__ __launch_bounds__(256) void prep_kernel(const float* __restrict__ wt,
                                                   const float* __restrict__ cmw,
                                                   short* __restrict__ wlin,
                                                   short* __restrict__ cwL)
{
    int i = blockIdx.x * 256 + threadIdx.x;
    if (i < 9*4096) {
        int k = i >> 12, r = i & 4095;
        int j = r >> 10, s = (r >> 9) & 1, lane = (r >> 3) & 63, e = i & 7;
        int o = j*16 + (lane & 15);
        int c = s*32 + ((lane >> 4) << 3) + e;
        wlin[i] = f2bf_s(wt[(o*64 + c)*9 + k]);
    }
    int jj = i - 9*4096;
    if (jj >= 0 && jj < NCH_*1024) {
        int CH = jj >> 10, s = (jj >> 9) & 1, lane = (jj >> 3) & 63, e = jj & 7;
        int o  = s*16 + (lane & 15);
        int kk = ((lane >> 4) << 3) + e;
        int k  = CH*32 + kk;
        short v = 0;
        if (o < 27 && k < 648) {
            int tap = k / 72, ch = k - (k/72)*72;
            v = f2bf_s(cmw[((size_t)o*72 + ch)*9 + tap]);
        }
        cwL[jj] = v;
    }
}

// ---------------------------------------------------------------------------
// xpose: NCHW f32 x -> bf16 NHWC xsb[px][0..63] (ch 64..71 filled by sim).
// ---------------------------------------------------------------------------
__global__ __launch_bounds__(128) void xpose_kernel(const float* __restrict__ x,
                                                    short* __restrict__ xsb)
{
    __shared__ float l[128][65];
    const int t = threadIdx.x;
    const int px0 = blockIdx.x * 128;
    const int b = px0 / HW_, p0 = px0 % HW_;
    for (int c = 0; c < 64; c++)
        l[t][c] = x[((size_t)(b*64 + c))*HW_ + p0 + t];
    __syncthreads();
#pragma unroll
    for (int rep = 0; rep < 16; rep++) {
        int pxl = (t >> 4) + rep*8;
        int c4  = (t & 15) * 4;
        bf16x4 v = { f2bf_s(l[pxl][c4]),   f2bf_s(l[pxl][c4+1]),
                     f2bf_s(l[pxl][c4+2]), f2bf_s(l[pxl][c4+3]) };
        *reinterpret_cast<bf16x4*>(&xsb[(size_t)(px0+pxl)*XC_ + c4]) = v;
    }
}

// ---------------------------------------------------------------------------
// sim: 4 threads/pixel (16-ch quarters), 2-level shfl_xor combine.
// 64-thread blocks, 16 px each, grid 5120. Writes xsb[px][64..71].
// ---------------------------------------------------------------------------
__global__ __launch_bounds__(64, 5) void sim_kernel(short* __restrict__ xsb)
{
    const int t = threadIdx.x;
    const int wg = blockIdx.x;
    const int sw = (wg & 7) * 640 + (wg >> 3);              // XCD-contiguous
    const int px = sw * 16 + (t >> 2);
    const int q = t & 3;
    const int w = px % W_, hh = (px / W_) % H_, b = px / HW_;

    const short* cen = xsb + (size_t)px * XC_ + q*16;
    float cv[16]; float ncc = 0.f;
#pragma unroll
    for (int s = 0; s < 2; s++) {
        bf16x8 cb = *reinterpret_cast<const bf16x8*>(cen + s*8);
#pragma unroll
        for (int j = 0; j < 8; j++) {
            float v = b2f(cb[j]);
            cv[s*8+j] = v;
            ncc = fmaf(v, v, ncc);
        }
    }

    const int kyA[8] = {-1,-1,-1, 0, 0, 1, 1, 1};
    const int kxA[8] = {-1, 0, 1,-1, 1,-1, 0, 1};
    float dot[8], nn[8];
#pragma unroll
    for (int n = 0; n < 8; n++) {
        int hn = hh + kyA[n], wn = w + kxA[n];
        bool v = (hn >= 0) & (hn < H_) & (wn >= 0) & (wn < W_);
        float msk = v ? 1.f : 0.f;
        const short* nb = xsb + (size_t)(b*HW_ + min(max(hn,0),H_-1)*W_ + min(max(wn,0),W_-1))*XC_ + q*16;
        float d = 0.f, s2 = 0.f;
#pragma unroll
        for (int s = 0; s < 2; s++) {
            bf16x8 qb = *reinterpret_cast<const bf16x8*>(nb + s*8);
#pragma unroll
            for (int j = 0; j < 8; j++) {
                float vv = b2f(qb[j]) * msk;
                d  = fmaf(cv[s*8+j], vv, d);
                s2 = fmaf(vv, vv, s2);
            }
        }
        dot[n] = d; nn[n] = s2;
    }
    ncc += __shfl_xor(ncc, 1); ncc += __shfl_xor(ncc, 2);
    const float ncr = 1.f / fmaxf(sqrtf(ncc), EPS_);
    float res[8];
#pragma unroll
    for (int n = 0; n < 8; n++) {
        float dt = dot[n]; dt += __shfl_xor(dt, 1); dt += __shfl_xor(dt, 2);
        float s2 = nn[n];  s2 += __shfl_xor(s2, 1); s2 += __shfl_xor(s2, 2);
        res[n] = dt * ncr / fmaxf(sqrtf(s2), EPS_);
    }
    if (q < 2) {
        bf16x4 r = { f2bf_s(res[q*4]),   f2bf_s(res[q*4+1]),
                     f2bf_s(res[q*4+2]), f2bf_s(res[q*4+3]) };
        *reinterpret_cast<bf16x4*>(xsb + (size_t)px * XC_ + 64 + q*4) = r;
    }
}

// ---------------------------------------------------------------------------
// cm: 3x3 conv 72->27 as bf16 MFMA implicit GEMM — barrier-free / LDS-free.
// 128-thread blocks (2 waves x 16px x 32o), grid 2560. W reads coalesced
// from cwL.
// ---------------------------------------------------------------------------
__global__ __launch_bounds__(128, 5) void cm_kernel(const short* __restrict__ xsb,
                                                    const short* __restrict__ cwL,
                                                    const float* __restrict__ cmb,
                                                    float* __restrict__ om)
{
    const int t  = threadIdx.x;
    const int wg = blockIdx.x;
    const int sw = (wg & 7) * 320 + (wg >> 3);              // XCD-contiguous
    const int px0 = sw * 32;
    const int lane = t & 63, wv = t >> 6;
    const int fr = lane & 15, fq = lane >> 4;

    const int pxs = px0 + wv*16 + fr;
    const int wsx = pxs % W_, hs = (pxs / W_) % H_, bs = pxs / HW_;
    const size_t xrow = (size_t)bs * HW_;

    f32x4 acc[2];
    acc[0] = (f32x4){0.f,0.f,0.f,0.f};
    acc[1] = (f32x4){0.f,0.f,0.f,0.f};

    bf16x8 G8; bf16x8 WF[2]; bool mskb;

#define CM_ISSUE_G(CH) do {                                                   \
    int k0_ = (CH)*32 + fq*8;                                                 \
    int tap_ = (k0_ * 911) >> 16;                                             \
    bool valid_ = (tap_ < 9);                                                 \
    tap_ = min(tap_, 8);                                                      \
    int ch_ = min(max(k0_ - tap_*72, 0), 64);                                 \
    int t3_ = (tap_ * 11) >> 5;                                               \
    int hy_ = hs + t3_ - 1, wx_ = wsx + (tap_ - t3_*3) - 1;                   \
    bool v_ = (hy_ >= 0) & (hy_ < H_) & (wx_ >= 0) & (wx_ < W_);              \
    mskb = v_ & valid_;                                                       \
    const short* src_ = xsb + (size_t)(xrow + min(max(hy_,0),H_-1)*W_         \
                                       + min(max(wx_,0),W_-1))*XC_ + ch_;     \
    G8 = *reinterpret_cast<const bf16x8*>(src_);                              \
  } while(0)

#define CM_ISSUE_W(CH) do {                                                   \
    const short* wp_ = cwL + (CH)*1024 + lane*8;                              \
    WF[0] = *reinterpret_cast<const bf16x8*>(wp_);                            \
    WF[1] = *reinterpret_cast<const bf16x8*>(wp_ + 512);                      \
  } while(0)

    CM_ISSUE_G(0);
    CM_ISSUE_W(0);

#pragma unroll 1
    for (int c = 0; c < NCH_; c++) {
        bf16x8 zero8 = {0,0,0,0,0,0,0,0};
        bf16x8 AF = mskb ? G8 : zero8;                      // exact binary mask
        bf16x8 W0 = WF[0], W1 = WF[1];
        if (c < NCH_-1) { CM_ISSUE_G(c+1); CM_ISSUE_W(c+1); }
        acc[0] = __builtin_amdgcn_mfma_f32_16x16x32_bf16(AF, W0, acc[0], 0,0,0);
        acc[1] = __builtin_amdgcn_mfma_f32_16x16x32_bf16(AF, W1, acc[1], 0,0,0);
    }

    const int pxr = px0 + wv*16 + fq*4;
#pragma unroll
    for (int j = 0; j < 2; j++) {
        int o = j*16 + fr;
        if (o < 27) {
            float bv = cmb[o];
#pragma unroll
            for (int r = 0; r < 4; r++)
                om[(size_t)(pxr + r) * OMC_ + o] = acc[j][r] + bv;
        }
    }
}

// ---------------------------------------------------------------------------
// dcn: bf16 MFMA implicit GEMM — barrier-free / LDS-free, explicit 2-deep
// gather pipeline with named ping-pong buffers (GA/GB) + meta prefetch.
// 256-thread blocks (4 waves x 16px x 64o), grid 1280. W-frags coalesced
// from wlin. __launch_bounds__(256,3): 170-VGPR budget for in-flight loads.
// ---------------------------------------------------------------------------
__global__ __launch_bounds__(256, 3) void dcn_kernel(const short* __restrict__ xsb,
                                                     const float* __restrict__ om,
                                                     const short* __restrict__ wlin,
                                                     const float* __restrict__ bias,
                                                     float* __restrict__ out)
{
    const int t  = threadIdx.x;
    const int wg = blockIdx.x;
    const int sw = (wg & 7) * 160 + (wg >> 3);              // XCD-contiguous
    const int px0 = sw * 64;
    const int lane = t & 63, wv = t >> 6;
    const int fr = lane & 15, fq = lane >> 4;
    const int ce = fq * 8;

    const int pxs = px0 + wv*16 + fr;
    const int wsx = pxs % W_, hs = (pxs / W_) % H_, bs = pxs / HW_;
    const float* omp = om + (size_t)pxs * OMC_;
    const size_t xrow = (size_t)bs * HW_;
    const short* wls = wlin + lane*8;                       // lane-folded base

    f32x4 acc[4];
#pragma unroll
    for (int j = 0; j < 4; j++) acc[j] = (f32x4){0.f,0.f,0.f,0.f};

#define DCN_META(KK, W00, W01, W10, W11, P0, P1, P2, P3) do {                 \
    float dy_ = omp[2*(KK)], dx_ = omp[2*(KK)+1], mz_ = omp[18+(KK)];         \
    float m_  = 1.f / (1.f + __expf(-mz_));                                   \
    float py_ = (float)(hs + (KK)/3 - 1) + dy_;                               \
    float px_ = (float)(wsx + (KK)%3 - 1) + dx_;                              \
    float y0f_ = floorf(py_), x0f_ = floorf(px_);                             \
    int   y0_ = (int)y0f_,   x0_ = (int)x0f_;                                 \
    float wy_ = py_ - y0f_,  wx_ = px_ - x0f_;                                \
    bool vy0_ = (y0_ >= 0)  & (y0_ < H_);                                     \
    bool vy1_ = (y0_ >= -1) & (y0_ < H_ - 1);                                 \
    bool vx0_ = (x0_ >= 0)  & (x0_ < W_);                                     \
    bool vx1_ = (x0_ >= -1) & (x0_ < W_ - 1);                                 \
    W00 = (1.f-wy_)*(1.f-wx_)*m_*((vy0_&vx0_)?1.f:0.f);                       \
    W01 = (1.f-wy_)*wx_      *m_*((vy0_&vx1_)?1.f:0.f);                       \
    W10 = wy_*(1.f-wx_)      *m_*((vy1_&vx0_)?1.f:0.f);                       \
    W11 = wy_*wx_            *m_*((vy1_&vx1_)?1.f:0.f);                       \
    int y0c_ = min(max(y0_,   0), H_-1), y1c_ = min(max(y0_+1, 0), H_-1);     \
    int x0c_ = min(max(x0_,   0), W_-1), x1c_ = min(max(x0_+1, 0), W_-1);     \
    P0 = xsb + (size_t)(xrow + y0c_*W_ + x0c_)*XC_ + ce;                      \
    P1 = xsb + (size_t)(xrow + y0c_*W_ + x1c_)*XC_ + ce;                      \
    P2 = xsb + (size_t)(xrow + y1c_*W_ + x0c_)*XC_ + ce;                      \
    P3 = xsb + (size_t)(xrow + y1c_*W_ + x1c_)*XC_ + ce;                      \
  } while(0)

#define DCN_GATHER(G, P0, P1, P2, P3) do {                                    \
    G[0] = *reinterpret_cast<const bf16x8*>(P0);                              \
    G[1] = *reinterpret_cast<const bf16x8*>(P0 + 32);                         \
    G[2] = *reinterpret_cast<const bf16x8*>(P1);                              \
    G[3] = *reinterpret_cast<const bf16x8*>(P1 + 32);                         \
    G[4] = *reinterpret_cast<const bf16x8*>(P2);                              \
    G[5] = *reinterpret_cast<const bf16x8*>(P2 + 32);                         \
    G[6] = *reinterpret_cast<const bf16x8*>(P3);                              \
    G[7] = *reinterpret_cast<const bf16x8*>(P3 + 32);                         \
  } while(0)

#define DCN_WLOAD(KK, WF) do {                                                \
    const short* wp_ = wls + (KK)*4096;                                       \
    WF[0] = *reinterpret_cast<const bf16x8*>(wp_);                            \
    WF[1] = *reinterpret_cast<const bf16x8*>(wp_ + 512);                      \
    WF[2] = *reinterpret_cast<const bf16x8*>(wp_ + 1024);                     \
    WF[3] = *reinterpret_cast<const bf16x8*>(wp_ + 1536);                     \
    WF[4] = *reinterpret_cast<const bf16x8*>(wp_ + 2048);                     \
    WF[5] = *reinterpret_cast<const bf16x8*>(wp_ + 2560);                     \
    WF[6] = *reinterpret_cast<const bf16x8*>(wp_ + 3072);                     \
    WF[7] = *reinterpret_cast<const bf16x8*>(wp_ + 3584);                     \
  } while(0)

#define DCN_COMBINE(G, W00, W01, W10, W11, AA, AB) do {                       \
    _Pragma("unroll")                                                         \
    for (int e_ = 0; e_ < 8; e_++)                                            \
        AA[e_] = f2bf_s(W00*b2f(G[0][e_]) + W01*b2f(G[2][e_])                 \
                      + W10*b2f(G[4][e_]) + W11*b2f(G[6][e_]));               \
    _Pragma("unroll")                                                         \
    for (int e_ = 0; e_ < 8; e_++)                                            \
        AB[e_] = f2bf_s(W00*b2f(G[1][e_]) + W01*b2f(G[3][e_])                 \
                      + W10*b2f(G[5][e_]) + W11*b2f(G[7][e_]));               \
  } while(0)

#define DCN_MFMA(WF, AA, AB) do {                                             \
    acc[0] = __builtin_amdgcn_mfma_f32_16x16x32_bf16(AA, WF[0], acc[0],0,0,0);\
    acc[0] = __builtin_amdgcn_mfma_f32_16x16x32_bf16(AB, WF[1], acc[0],0,0,0);\
    acc[1] = __builtin_amdgcn_mfma_f32_16x16x32_bf16(AA, WF[2], acc[1],0,0,0);\
    acc[1] = __builtin_amdgcn_mfma_f32_16x16x32_bf16(AB, WF[3], acc[1],0,0,0);\
    acc[2] = __builtin_amdgcn_mfma_f32_16x16x32_bf16(AA, WF[4], acc[2],0,0,0);\
    acc[2] = __builtin_amdgcn_mfma_f32_16x16x32_bf16(AB, WF[5], acc[2],0,0,0);\
    acc[3] = __builtin_amdgcn_mfma_f32_16x16x32_bf16(AA, WF[6], acc[3],0,0,0);\
    acc[3] = __builtin_amdgcn_mfma_f32_16x16x32_bf16(AB, WF[7], acc[3],0,0,0);\
  } while(0)

    // ---- prologue: meta(0) + GA(0) in flight; meta(1) ready ----
    float wA00, wA01, wA10, wA11; const short *pA0, *pA1, *pA2, *pA3;
    float wB00, wB01, wB10, wB11; const short *pB0, *pB1, *pB2, *pB3;
    bf16x8 GA[8], GB[8];

    DCN_META(0, wA00,wA01,wA10,wA11, pA0,pA1,pA2,pA3);
    DCN_GATHER(GA, pA0,pA1,pA2,pA3);
    DCN_META(1, wB00,wB01,wB10,wB11, pB0,pB1,pB2,pB3);

#pragma unroll 1
    for (int kp = 0; kp < 4; kp++) {
        const int ke = kp*2;
        // ---- tap ke (even): GA holds data, wA holds weights ----
        DCN_GATHER(GB, pB0,pB1,pB2,pB3);                // tap ke+1 in flight
        bf16x8 WE[8]; DCN_WLOAD(ke, WE);                // coalesced
        float nA00,nA01,nA10,nA11; const short *qA0,*qA1,*qA2,*qA3;
        DCN_META(ke+2, nA00,nA01,nA10,nA11, qA0,qA1,qA2,qA3);   // ke+2 <= 8
        bf16x8 aA, aB; DCN_COMBINE(GA, wA00,wA01,wA10,wA11, aA, aB);
        DCN_MFMA(WE, aA, aB);
        wA00=nA00; wA01=nA01; wA10=nA10; wA11=nA11;
        pA0=qA0; pA1=qA1; pA2=qA2; pA3=qA3;
        DCN_GATHER(GA, pA0,pA1,pA2,pA3);                // tap ke+2 in flight

        // ---- tap ke+1 (odd): GB holds data, wB holds weights ----
        bf16x8 WO[8]; DCN_WLOAD(ke+1, WO);
        float nB00,nB01,nB10,nB11; const short *qB0,*qB1,*qB2,*qB3;
        if (kp < 3) {
            DCN_META(ke+3, nB00,nB01,nB10,nB11, qB0,qB1,qB2,qB3);
        } else {
            nB00=wB00; nB01=wB01; nB10=wB10; nB11=wB11;
            qB0=pB0; qB1=pB1; qB2=pB2; qB3=pB3;
        }
        bf16x8 cA, cB; DCN_COMBINE(GB, wB00,wB01,wB10,wB11, cA, cB);
        DCN_MFMA(WO, cA, cB);
        wB00=nB00; wB01=nB01; wB10=nB10; wB11=nB11;
        pB0=qB0; pB1=qB1; pB2=qB2; pB3=qB3;
    }

    // ---- tap 8 (in GA / wA) ----
    {
        bf16x8 WE[8]; DCN_WLOAD(8, WE);
        bf16x8 aA, aB; DCN_COMBINE(GA, wA00,wA01,wA10,wA11, aA, aB);
        DCN_MFMA(WE, aA, aB);
    }

    // ---- epilogue: D row px = wv*16 + fq*4 + reg, col o = j*16 + fr ----
    const int bo = px0 / HW_, po = px0 % HW_;
#pragma unroll
    for (int j = 0; j < 4; j++) {
        int o = j*16 + fr;
        float bv = bias[o];
        f4 r = { acc[j][0] + bv, acc[j][1] + bv, acc[j][2] + bv, acc[j][3] + bv };
        *reinterpret_cast<f4*>(&out[((size_t)(bo*64 + o))*HW_ + po + wv*16 + fq*4]) = r;
    }
}

// ---------------------------------------------------------------------------
extern "C" void kernel_launch(void* const* d_in, const int* in_sizes, int n_in,
                              void* d_out, int out_size, void* d_ws, size_t ws_size,
                              hipStream_t stream)
{
    const float* x   = (const float*)d_in[0];
    const float* wt  = (const float*)d_in[1];
    const float* bs  = (const float*)d_in[2];
    const float* cmw = (const float*)d_in[3];
    const float* cmb = (const float*)d_in[4];
    float* out = (float*)d_out;

    float* om   = (float*)d_ws;                             // NPIX_*28 f32
    short* xsb  = (short*)(om + (size_t)NPIX_ * OMC_);      // NPIX_*72 bf16
    short* wlin = xsb + (size_t)NPIX_ * XC_;                // 9*4096 bf16
    short* cwL  = wlin + 9*4096;                            // 21*1024 bf16

    prep_kernel <<<228, 256, 0, stream>>>(wt, cmw, wlin, cwL);
    xpose_kernel<<<NPIX_/128, 128, 0, stream>>>(x, xsb);
    sim_kernel  <<<NPIX_/16,  64,  0, stream>>>(xsb);
    cm_kernel   <<<NPIX_/32,  128, 0, stream>>>(xsb, cwL, cmb, om);
    dcn_kernel  <<<NPIX_/64,  256, 0, stream>>>(xsb, om, wlin, bs, out);
}

// Round 11
// 98.163 us; speedup vs baseline: 1.5235x; 1.0408x over previous
//
#include <hip/hip_runtime.h>
#include <hip/hip_bf16.h>
#include <math.h>

#define B_    4
#define CIN_  64
#define COUT_ 64
#define H_    128
#define W_    160
#define HW_   (H_*W_)
#define NPIX_ (B_*HW_)      // 81920
#define XC_   72            // xsb channel stride: x(64) + sim(8), bf16
#define OMC_  28            // om channels padded (27 used)
#define EPS_  1e-8f
#define NCH_  21            // cm K-chunks: ceil(648/32)

typedef float  f4     __attribute__((ext_vector_type(4)));
typedef float  f32x4  __attribute__((ext_vector_type(4)));
typedef short  bf16x8 __attribute__((ext_vector_type(8)));
typedef short  bf16x4 __attribute__((ext_vector_type(4)));

static __device__ __forceinline__ short f2bf_s(float f) {
    __hip_bfloat16 h = __float2bfloat16(f);
    return *reinterpret_cast<short*>(&h);
}
static __device__ __forceinline__ float b2f(short s) {
    union { unsigned u; float f; } cv;
    cv.u = ((unsigned)(unsigned short)s) << 16;
    return cv.f;
}

// ---------------------------------------------------------------------------
// prep:
//  wlin[k][j][s][lane][8] bf16 (9*4096): dcn W-fragments PRE-LINEARIZED so a
//    wave reads each (j,s) fragment as ONE coalesced 1KB load at lane*16B.
//    element: o = j*16+(lane&15), c = s*32+(lane>>4)*8+e.
//  cwL[CH][s][lane][8] bf16 (21*1024): cm W-fragments, same linearization.
//    element: o = s*16+(lane&15), k = CH*32+(lane>>4)*8+e (zero-padded).
// ---------------------------------------------------------------------------
__global__ __launch_bounds__(256) void prep_kernel(const float* __restrict__ wt,
                                                   const float* __restrict__ cmw,
                                                   short* __restrict__ wlin,
                                                   short* __restrict__ cwL)
{
    int i = blockIdx.x * 256 + threadIdx.x;
    if (i < 9*4096) {
        int k = i >> 12, r = i & 4095;
        int j = r >> 10, s = (r >> 9) & 1, lane = (r >> 3) & 63, e = i & 7;
        int o = j*16 + (lane & 15);
        int c = s*32 + ((lane >> 4) << 3) + e;
        wlin[i] = f2bf_s(wt[(o*64 + c)*9 + k]);
    }
    int jj = i - 9*4096;
    if (jj >= 0 && jj < NCH_*1024) {
        int CH = jj >> 10, s = (jj >> 9) & 1, lane = (jj >> 3) & 63, e = jj & 7;
        int o  = s*16 + (lane & 15);
        int kk = ((lane >> 4) << 3) + e;
        int k  = CH*32 + kk;
        short v = 0;
        if (o < 27 && k < 648) {
            int tap = k / 72, ch = k - (k/72)*72;
            v = f2bf_s(cmw[((size_t)o*72 + ch)*9 + tap]);
        }
        cwL[jj] = v;
    }
}

// ---------------------------------------------------------------------------
// xpose: NCHW f32 x -> bf16 NHWC xsb[px][0..63] (ch 64..71 filled by sim).
// ---------------------------------------------------------------------------
__global__ __launch_bounds__(128) void xpose_kernel(const float* __restrict__ x,
                                                    short* __restrict__ xsb)
{
    __shared__ float l[128][65];
    const int t = threadIdx.x;
    const int px0 = blockIdx.x * 128;
    const int b = px0 / HW_, p0 = px0 % HW_;
    for (int c = 0; c < 64; c++)
        l[t][c] = x[((size_t)(b*64 + c))*HW_ + p0 + t];
    __syncthreads();
#pragma unroll
    for (int rep = 0; rep < 16; rep++) {
        int pxl = (t >> 4) + rep*8;
        int c4  = (t & 15) * 4;
        bf16x4 v = { f2bf_s(l[pxl][c4]),   f2bf_s(l[pxl][c4+1]),
                     f2bf_s(l[pxl][c4+2]), f2bf_s(l[pxl][c4+3]) };
        *reinterpret_cast<bf16x4*>(&xsb[(size_t)(px0+pxl)*XC_ + c4]) = v;
    }
}

// ---------------------------------------------------------------------------
// sim: 4 threads/pixel (16-ch quarters), 2-level shfl_xor combine.
// 64-thread blocks, 16 px each, grid 5120. Writes xsb[px][64..71].
// ---------------------------------------------------------------------------
__global__ __launch_bounds__(64, 5) void sim_kernel(short* __restrict__ xsb)
{
    const int t = threadIdx.x;
    const int wg = blockIdx.x;
    const int sw = (wg & 7) * 640 + (wg >> 3);              // XCD-contiguous
    const int px = sw * 16 + (t >> 2);
    const int q = t & 3;
    const int w = px % W_, hh = (px / W_) % H_, b = px / HW_;

    const short* cen = xsb + (size_t)px * XC_ + q*16;
    float cv[16]; float ncc = 0.f;
#pragma unroll
    for (int s = 0; s < 2; s++) {
        bf16x8 cb = *reinterpret_cast<const bf16x8*>(cen + s*8);
#pragma unroll
        for (int j = 0; j < 8; j++) {
            float v = b2f(cb[j]);
            cv[s*8+j] = v;
            ncc = fmaf(v, v, ncc);
        }
    }

    const int kyA[8] = {-1,-1,-1, 0, 0, 1, 1, 1};
    const int kxA[8] = {-1, 0, 1,-1, 1,-1, 0, 1};
    float dot[8], nn[8];
#pragma unroll
    for (int n = 0; n < 8; n++) {
        int hn = hh + kyA[n], wn = w + kxA[n];
        bool v = (hn >= 0) & (hn < H_) & (wn >= 0) & (wn < W_);
        float msk = v ? 1.f : 0.f;
        const short* nb = xsb + (size_t)(b*HW_ + min(max(hn,0),H_-1)*W_ + min(max(wn,0),W_-1))*XC_ + q*16;
        float d = 0.f, s2 = 0.f;
#pragma unroll
        for (int s = 0; s < 2; s++) {
            bf16x8 qb = *reinterpret_cast<const bf16x8*>(nb + s*8);
#pragma unroll
            for (int j = 0; j < 8; j++) {
                float vv = b2f(qb[j]) * msk;
                d  = fmaf(cv[s*8+j], vv, d);
                s2 = fmaf(vv, vv, s2);
            }
        }
        dot[n] = d; nn[n] = s2;
    }
    ncc += __shfl_xor(ncc, 1); ncc += __shfl_xor(ncc, 2);
    const float ncr = 1.f / fmaxf(sqrtf(ncc), EPS_);
    float res[8];
#pragma unroll
    for (int n = 0; n < 8; n++) {
        float dt = dot[n]; dt += __shfl_xor(dt, 1); dt += __shfl_xor(dt, 2);
        float s2 = nn[n];  s2 += __shfl_xor(s2, 1); s2 += __shfl_xor(s2, 2);
        res[n] = dt * ncr / fmaxf(sqrtf(s2), EPS_);
    }
    if (q < 2) {
        bf16x4 r = { f2bf_s(res[q*4]),   f2bf_s(res[q*4+1]),
                     f2bf_s(res[q*4+2]), f2bf_s(res[q*4+3]) };
        *reinterpret_cast<bf16x4*>(xsb + (size_t)px * XC_ + 64 + q*4) = r;
    }
}

// ---------------------------------------------------------------------------
// cm: 3x3 conv 72->27 as bf16 MFMA implicit GEMM — barrier-free / LDS-free.
// 128-thread blocks (2 waves x 16px x 32o), grid 2560. W reads coalesced
// from cwL.
// ---------------------------------------------------------------------------
__global__ __launch_bounds__(128, 5) void cm_kernel(const short* __restrict__ xsb,
                                                    const short* __restrict__ cwL,
                                                    const float* __restrict__ cmb,
                                                    float* __restrict__ om)
{
    const int t  = threadIdx.x;
    const int wg = blockIdx.x;
    const int sw = (wg & 7) * 320 + (wg >> 3);              // XCD-contiguous
    const int px0 = sw * 32;
    const int lane = t & 63, wv = t >> 6;
    const int fr = lane & 15, fq = lane >> 4;

    const int pxs = px0 + wv*16 + fr;
    const int wsx = pxs % W_, hs = (pxs / W_) % H_, bs = pxs / HW_;
    const size_t xrow = (size_t)bs * HW_;

    f32x4 acc[2];
    acc[0] = (f32x4){0.f,0.f,0.f,0.f};
    acc[1] = (f32x4){0.f,0.f,0.f,0.f};

    bf16x8 G8; bf16x8 WF[2]; bool mskb;

#define CM_ISSUE_G(CH) do {                                                   \
    int k0_ = (CH)*32 + fq*8;                                                 \
    int tap_ = (k0_ * 911) >> 16;                                             \
    bool valid_ = (tap_ < 9);                                                 \
    tap_ = min(tap_, 8);                                                      \
    int ch_ = min(max(k0_ - tap_*72, 0), 64);                                 \
    int t3_ = (tap_ * 11) >> 5;                                               \
    int hy_ = hs + t3_ - 1, wx_ = wsx + (tap_ - t3_*3) - 1;                   \
    bool v_ = (hy_ >= 0) & (hy_ < H_) & (wx_ >= 0) & (wx_ < W_);              \
    mskb = v_ & valid_;                                                       \
    const short* src_ = xsb + (size_t)(xrow + min(max(hy_,0),H_-1)*W_         \
                                       + min(max(wx_,0),W_-1))*XC_ + ch_;     \
    G8 = *reinterpret_cast<const bf16x8*>(src_);                              \
  } while(0)

#define CM_ISSUE_W(CH) do {                                                   \
    const short* wp_ = cwL + (CH)*1024 + lane*8;                              \
    WF[0] = *reinterpret_cast<const bf16x8*>(wp_);                            \
    WF[1] = *reinterpret_cast<const bf16x8*>(wp_ + 512);                      \
  } while(0)

    CM_ISSUE_G(0);
    CM_ISSUE_W(0);

#pragma unroll 1
    for (int c = 0; c < NCH_; c++) {
        bf16x8 zero8 = {0,0,0,0,0,0,0,0};
        bf16x8 AF = mskb ? G8 : zero8;                      // exact binary mask
        bf16x8 W0 = WF[0], W1 = WF[1];
        if (c < NCH_-1) { CM_ISSUE_G(c+1); CM_ISSUE_W(c+1); }
        acc[0] = __builtin_amdgcn_mfma_f32_16x16x32_bf16(AF, W0, acc[0], 0,0,0);
        acc[1] = __builtin_amdgcn_mfma_f32_16x16x32_bf16(AF, W1, acc[1], 0,0,0);
    }

    const int pxr = px0 + wv*16 + fq*4;
#pragma unroll
    for (int j = 0; j < 2; j++) {
        int o = j*16 + fr;
        if (o < 27) {
            float bv = cmb[o];
#pragma unroll
            for (int r = 0; r < 4; r++)
                om[(size_t)(pxr + r) * OMC_ + o] = acc[j][r] + bv;
        }
    }
}

// ---------------------------------------------------------------------------
// dcn: bf16 MFMA implicit GEMM. W for taps 0..7 staged in 64KB LDS once per
// block (FIXED: 16 x 256-thread chunks fill all 4096 chunks — R10 only
// filled half -> NaN). Per-tap W reads are ds_read (lgkm queue, off the
// vmcnt path so the 8 scattered gathers batch into one latency per tap).
// Tap 8's W from global. 2-deep GA/GB gather ping-pong; (256,2) VGPR budget.
// ---------------------------------------------------------------------------
__global__ __launch_bounds__(256, 2) void dcn_kernel(const short* __restrict__ xsb,
                                                     const float* __restrict__ om,
                                                     const short* __restrict__ wlin,
                                                     const float* __restrict__ bias,
                                                     float* __restrict__ out)
{
    __shared__ __align__(16) short WL[8*4096];              // 64KB: taps 0..7

    const int t  = threadIdx.x;
    const int wg = blockIdx.x;
    const int sw = (wg & 7) * 160 + (wg >> 3);              // XCD-contiguous
    const int px0 = sw * 64;
    const int lane = t & 63, wv = t >> 6;
    const int fr = lane & 15, fq = lane >> 4;
    const int ce = fq * 8;

    // ---- stage W taps 0..7 into LDS: 4096 chunks = 16 rounds x 256 thr ----
#pragma unroll
    for (int r = 0; r < 16; r++) {
        int ch = r*256 + t;
        *reinterpret_cast<bf16x8*>(&WL[ch*8]) =
            *reinterpret_cast<const bf16x8*>(wlin + ch*8);
    }
    __syncthreads();

    const int pxs = px0 + wv*16 + fr;
    const int wsx = pxs % W_, hs = (pxs / W_) % H_, bs = pxs / HW_;
    const float* omp = om + (size_t)pxs * OMC_;
    const size_t xrow = (size_t)bs * HW_;
    const int lb = lane*8;                                  // lane offset in W frag

    f32x4 acc[4];
#pragma unroll
    for (int j = 0; j < 4; j++) acc[j] = (f32x4){0.f,0.f,0.f,0.f};

#define DCN_META(KK, W00, W01, W10, W11, P0, P1, P2, P3) do {                 \
    float dy_ = omp[2*(KK)], dx_ = omp[2*(KK)+1], mz_ = omp[18+(KK)];         \
    float m_  = 1.f / (1.f + __expf(-mz_));                                   \
    float py_ = (float)(hs + (KK)/3 - 1) + dy_;                               \
    float px_ = (float)(wsx + (KK)%3 - 1) + dx_;                              \
    float y0f_ = floorf(py_), x0f_ = floorf(px_);                             \
    int   y0_ = (int)y0f_,   x0_ = (int)x0f_;                                 \
    float wy_ = py_ - y0f_,  wx_ = px_ - x0f_;                                \
    bool vy0_ = (y0_ >= 0)  & (y0_ < H_);                                     \
    bool vy1_ = (y0_ >= -1) & (y0_ < H_ - 1);                                 \
    bool vx0_ = (x0_ >= 0)  & (x0_ < W_);                                     \
    bool vx1_ = (x0_ >= -1) & (x0_ < W_ - 1);                                 \
    W00 = (1.f-wy_)*(1.f-wx_)*m_*((vy0_&vx0_)?1.f:0.f);                       \
    W01 = (1.f-wy_)*wx_      *m_*((vy0_&vx1_)?1.f:0.f);                       \
    W10 = wy_*(1.f-wx_)      *m_*((vy1_&vx0_)?1.f:0.f);                       \
    W11 = wy_*wx_            *m_*((vy1_&vx1_)?1.f:0.f);                       \
    int y0c_ = min(max(y0_,   0), H_-1), y1c_ = min(max(y0_+1, 0), H_-1);     \
    int x0c_ = min(max(x0_,   0), W_-1), x1c_ = min(max(x0_+1, 0), W_-1);     \
    P0 = xsb + (size_t)(xrow + y0c_*W_ + x0c_)*XC_ + ce;                      \
    P1 = xsb + (size_t)(xrow + y0c_*W_ + x1c_)*XC_ + ce;                      \
    P2 = xsb + (size_t)(xrow + y1c_*W_ + x0c_)*XC_ + ce;                      \
    P3 = xsb + (size_t)(xrow + y1c_*W_ + x1c_)*XC_ + ce;                      \
  } while(0)

#define DCN_GATHER(G, P0, P1, P2, P3) do {                                    \
    G[0] = *reinterpret_cast<const bf16x8*>(P0);                              \
    G[1] = *reinterpret_cast<const bf16x8*>(P0 + 32);                         \
    G[2] = *reinterpret_cast<const bf16x8*>(P1);                              \
    G[3] = *reinterpret_cast<const bf16x8*>(P1 + 32);                         \
    G[4] = *reinterpret_cast<const bf16x8*>(P2);                              \
    G[5] = *reinterpret_cast<const bf16x8*>(P2 + 32);                         \
    G[6] = *reinterpret_cast<const bf16x8*>(P3);                              \
    G[7] = *reinterpret_cast<const bf16x8*>(P3 + 32);                         \
  } while(0)

#define DCN_WLDS(KK, WF) do {                                                 \
    const int wb_ = (KK)*4096 + lb;                                           \
    WF[0] = *reinterpret_cast<const bf16x8*>(&WL[wb_]);                       \
    WF[1] = *reinterpret_cast<const bf16x8*>(&WL[wb_ + 512]);                 \
    WF[2] = *reinterpret_cast<const bf16x8*>(&WL[wb_ + 1024]);                \
    WF[3] = *reinterpret_cast<const bf16x8*>(&WL[wb_ + 1536]);                \
    WF[4] = *reinterpret_cast<const bf16x8*>(&WL[wb_ + 2048]);                \
    WF[5] = *reinterpret_cast<const bf16x8*>(&WL[wb_ + 2560]);                \
    WF[6] = *reinterpret_cast<const bf16x8*>(&WL[wb_ + 3072]);                \
    WF[7] = *reinterpret_cast<const bf16x8*>(&WL[wb_ + 3584]);                \
  } while(0)

#define DCN_WGLB(KK, WF) do {                                                 \
    const short* wp_ = wlin + (KK)*4096 + lb;                                 \
    WF[0] = *reinterpret_cast<const bf16x8*>(wp_);                            \
    WF[1] = *reinterpret_cast<const bf16x8*>(wp_ + 512);                      \
    WF[2] = *reinterpret_cast<const bf16x8*>(wp_ + 1024);                     \
    WF[3] = *reinterpret_cast<const bf16x8*>(wp_ + 1536);                     \
    WF[4] = *reinterpret_cast<const bf16x8*>(wp_ + 2048);                     \
    WF[5] = *reinterpret_cast<const bf16x8*>(wp_ + 2560);                     \
    WF[6] = *reinterpret_cast<const bf16x8*>(wp_ + 3072);                     \
    WF[7] = *reinterpret_cast<const bf16x8*>(wp_ + 3584);                     \
  } while(0)

#define DCN_COMBINE(G, W00, W01, W10, W11, AA, AB) do {                       \
    _Pragma("unroll")                                                         \
    for (int e_ = 0; e_ < 8; e_++)                                            \
        AA[e_] = f2bf_s(W00*b2f(G[0][e_]) + W01*b2f(G[2][e_])                 \
                      + W10*b2f(G[4][e_]) + W11*b2f(G[6][e_]));               \
    _Pragma("unroll")                                                         \
    for (int e_ = 0; e_ < 8; e_++)                                            \
        AB[e_] = f2bf_s(W00*b2f(G[1][e_]) + W01*b2f(G[3][e_])                 \
                      + W10*b2f(G[5][e_]) + W11*b2f(G[7][e_]));               \
  } while(0)

#define DCN_MFMA(WF, AA, AB) do {                                             \
    acc[0] = __builtin_amdgcn_mfma_f32_16x16x32_bf16(AA, WF[0], acc[0],0,0,0);\
    acc[0] = __builtin_amdgcn_mfma_f32_16x16x32_bf16(AB, WF[1], acc[0],0,0,0);\
    acc[1] = __builtin_amdgcn_mfma_f32_16x16x32_bf16(AA, WF[2], acc[1],0,0,0);\
    acc[1] = __builtin_amdgcn_mfma_f32_16x16x32_bf16(AB, WF[3], acc[1],0,0,0);\
    acc[2] = __builtin_amdgcn_mfma_f32_16x16x32_bf16(AA, WF[4], acc[2],0,0,0);\
    acc[2] = __builtin_amdgcn_mfma_f32_16x16x32_bf16(AB, WF[5], acc[2],0,0,0);\
    acc[3] = __builtin_amdgcn_mfma_f32_16x16x32_bf16(AA, WF[6], acc[3],0,0,0);\
    acc[3] = __builtin_amdgcn_mfma_f32_16x16x32_bf16(AB, WF[7], acc[3],0,0,0);\
  } while(0)

    // ---- prologue: meta(0) + GA(0) in flight; meta(1) ready ----
    float wA00, wA01, wA10, wA11; const short *pA0, *pA1, *pA2, *pA3;
    float wB00, wB01, wB10, wB11; const short *pB0, *pB1, *pB2, *pB3;
    bf16x8 GA[8], GB[8];

    DCN_META(0, wA00,wA01,wA10,wA11, pA0,pA1,pA2,pA3);
    DCN_GATHER(GA, pA0,pA1,pA2,pA3);
    DCN_META(1, wB00,wB01,wB10,wB11, pB0,pB1,pB2,pB3);

#pragma unroll 1
    for (int kp = 0; kp < 4; kp++) {
        const int ke = kp*2;
        // ---- tap ke (even): GA holds data, wA holds weights ----
        DCN_GATHER(GB, pB0,pB1,pB2,pB3);                // tap ke+1 in flight
        bf16x8 WE[8]; DCN_WLDS(ke, WE);                 // lgkm, overlaps vmem
        float nA00,nA01,nA10,nA11; const short *qA0,*qA1,*qA2,*qA3;
        DCN_META(ke+2, nA00,nA01,nA10,nA11, qA0,qA1,qA2,qA3);   // ke+2 <= 8
        bf16x8 aA, aB; DCN_COMBINE(GA, wA00,wA01,wA10,wA11, aA, aB);
        DCN_MFMA(WE, aA, aB);
        wA00=nA00; wA01=nA01; wA10=nA10; wA11=nA11;
        pA0=qA0; pA1=qA1; pA2=qA2; pA3=qA3;
        DCN_GATHER(GA, pA0,pA1,pA2,pA3);                // tap ke+2 in flight

        // ---- tap ke+1 (odd): GB holds data, wB holds weights ----
        bf16x8 WO[8]; DCN_WLDS(ke+1, WO);
        float nB00,nB01,nB10,nB11; const short *qB0,*qB1,*qB2,*qB3;
        if (kp < 3) {
            DCN_META(ke+3, nB00,nB01,nB10,nB11, qB0,qB1,qB2,qB3);
        } else {
            nB00=wB00; nB01=wB01; nB10=wB10; nB11=wB11;
            qB0=pB0; qB1=pB1; qB2=pB2; qB3=pB3;
        }
        bf16x8 cA, cB; DCN_COMBINE(GB, wB00,wB01,wB10,wB11, cA, cB);
        DCN_MFMA(WO, cA, cB);
        wB00=nB00; wB01=nB01; wB10=nB10; wB11=nB11;
        pB0=qB0; pB1=qB1; pB2=qB2; pB3=qB3;
    }

    // ---- tap 8 (in GA / wA), W from global ----
    {
        bf16x8 WE[8]; DCN_WGLB(8, WE);
        bf16x8 aA, aB; DCN_COMBINE(GA, wA00,wA01,wA10,wA11, aA, aB);
        DCN_MFMA(WE, aA, aB);
    }

    // ---- epilogue: D row px = wv*16 + fq*4 + reg, col o = j*16 + fr ----
    const int bo = px0 / HW_, po = px0 % HW_;
#pragma unroll
    for (int j = 0; j < 4; j++) {
        int o = j*16 + fr;
        float bv = bias[o];
        f4 r = { acc[j][0] + bv, acc[j][1] + bv, acc[j][2] + bv, acc[j][3] + bv };
        *reinterpret_cast<f4*>(&out[((size_t)(bo*64 + o))*HW_ + po + wv*16 + fq*4]) = r;
    }
}

// ---------------------------------------------------------------------------
extern "C" void kernel_launch(void* const* d_in, const int* in_sizes, int n_in,
                              void* d_out, int out_size, void* d_ws, size_t ws_size,
                              hipStream_t stream)
{
    const float* x   = (const float*)d_in[0];
    const float* wt  = (const float*)d_in[1];
    const float* bs  = (const float*)d_in[2];
    const float* cmw = (const float*)d_in[3];
    const float* cmb = (const float*)d_in[4];
    float* out = (float*)d_out;

    float* om   = (float*)d_ws;                             // NPIX_*28 f32
    short* xsb  = (short*)(om + (size_t)NPIX_ * OMC_);      // NPIX_*72 bf16
    short* wlin = xsb + (size_t)NPIX_ * XC_;                // 9*4096 bf16
    short* cwL  = wlin + 9*4096;                            // 21*1024 bf16

    prep_kernel <<<228, 256, 0, stream>>>(wt, cmw, wlin, cwL);
    xpose_kernel<<<NPIX_/128, 128, 0, stream>>>(x, xsb);
    sim_kernel  <<<NPIX_/16,  64,  0, stream>>>(xsb);
    cm_kernel   <<<NPIX_/32,  128, 0, stream>>>(xsb, cwL, cmb, om);
    dcn_kernel  <<<NPIX_/64,  256, 0, stream>>>(xsb, om, wlin, bs, out);
}

// Round 12
// 95.932 us; speedup vs baseline: 1.5589x; 1.0233x over previous
//
#include <hip/hip_runtime.h>
#include <hip/hip_bf16.h>
#include <math.h>

#define B_    4
#define CIN_  64
#define COUT_ 64
#define H_    128
#define W_    160
#define HW_   (H_*W_)
#define NPIX_ (B_*HW_)      // 81920
#define XC_   72            // xsb channel stride: x(64) + sim(8), bf16
#define EPS_  1e-8f
#define NCH_  21            // cm K-chunks: ceil(648/32)

typedef float  f4     __attribute__((ext_vector_type(4)));
typedef float  f32x4  __attribute__((ext_vector_type(4)));
typedef short  bf16x8 __attribute__((ext_vector_type(8)));
typedef short  bf16x4 __attribute__((ext_vector_type(4)));

static __device__ __forceinline__ short f2bf_s(float f) {
    __hip_bfloat16 h = __float2bfloat16(f);
    return *reinterpret_cast<short*>(&h);
}
static __device__ __forceinline__ float b2f(short s) {
    union { unsigned u; float f; } cv;
    cv.u = ((unsigned)(unsigned short)s) << 16;
    return cv.f;
}

// ---------------------------------------------------------------------------
// prep:
//  wlin[k][j][s][lane][8] bf16 (9*4096): dcn W-fragments PRE-LINEARIZED so a
//    wave reads each (j,s) fragment as ONE coalesced 1KB load at lane*16B.
//    element: o = j*16+(lane&15), c = s*32+(lane>>4)*8+e.
//  cwL[CH][s][lane][8] bf16 (21*1024): cm W-fragments, same linearization.
//    element: o = s*16+(lane&15), k = CH*32+(lane>>4)*8+e (zero-padded).
// ---------------------------------------------------------------------------
__global__ __launch_bounds__(256) void prep_kernel(const float* __restrict__ wt,
                                                   const float* __restrict__ cmw,
                                                   short* __restrict__ wlin,
                                                   short* __restrict__ cwL)
{
    int i = blockIdx.x * 256 + threadIdx.x;
    if (i < 9*4096) {
        int k = i >> 12, r = i & 4095;
        int j = r >> 10, s = (r >> 9) & 1, lane = (r >> 3) & 63, e = i & 7;
        int o = j*16 + (lane & 15);
        int c = s*32 + ((lane >> 4) << 3) + e;
        wlin[i] = f2bf_s(wt[(o*64 + c)*9 + k]);
    }
    int jj = i - 9*4096;
    if (jj >= 0 && jj < NCH_*1024) {
        int CH = jj >> 10, s = (jj >> 9) & 1, lane = (jj >> 3) & 63, e = jj & 7;
        int o  = s*16 + (lane & 15);
        int kk = ((lane >> 4) << 3) + e;
        int k  = CH*32 + kk;
        short v = 0;
        if (o < 27 && k < 648) {
            int tap = k / 72, ch = k - (k/72)*72;
            v = f2bf_s(cmw[((size_t)o*72 + ch)*9 + tap]);
        }
        cwL[jj] = v;
    }
}

// ---------------------------------------------------------------------------
// xpose: NCHW f32 x -> bf16 NHWC xsb[px][0..63] (ch 64..71 filled by sim).
// ---------------------------------------------------------------------------
__global__ __launch_bounds__(128) void xpose_kernel(const float* __restrict__ x,
                                                    short* __restrict__ xsb)
{
    __shared__ float l[128][65];
    const int t = threadIdx.x;
    const int px0 = blockIdx.x * 128;
    const int b = px0 / HW_, p0 = px0 % HW_;
    for (int c = 0; c < 64; c++)
        l[t][c] = x[((size_t)(b*64 + c))*HW_ + p0 + t];
    __syncthreads();
#pragma unroll
    for (int rep = 0; rep < 16; rep++) {
        int pxl = (t >> 4) + rep*8;
        int c4  = (t & 15) * 4;
        bf16x4 v = { f2bf_s(l[pxl][c4]),   f2bf_s(l[pxl][c4+1]),
                     f2bf_s(l[pxl][c4+2]), f2bf_s(l[pxl][c4+3]) };
        *reinterpret_cast<bf16x4*>(&xsb[(size_t)(px0+pxl)*XC_ + c4]) = v;
    }
}

// ---------------------------------------------------------------------------
// sim: 4 threads/pixel (16-ch quarters), 2-level shfl_xor combine.
// 64-thread blocks, 16 px each, grid 5120. Writes xsb[px][64..71].
// ---------------------------------------------------------------------------
__global__ __launch_bounds__(64, 5) void sim_kernel(short* __restrict__ xsb)
{
    const int t = threadIdx.x;
    const int wg = blockIdx.x;
    const int sw = (wg & 7) * 640 + (wg >> 3);              // XCD-contiguous
    const int px = sw * 16 + (t >> 2);
    const int q = t & 3;
    const int w = px % W_, hh = (px / W_) % H_, b = px / HW_;

    const short* cen = xsb + (size_t)px * XC_ + q*16;
    float cv[16]; float ncc = 0.f;
#pragma unroll
    for (int s = 0; s < 2; s++) {
        bf16x8 cb = *reinterpret_cast<const bf16x8*>(cen + s*8);
#pragma unroll
        for (int j = 0; j < 8; j++) {
            float v = b2f(cb[j]);
            cv[s*8+j] = v;
            ncc = fmaf(v, v, ncc);
        }
    }

    const int kyA[8] = {-1,-1,-1, 0, 0, 1, 1, 1};
    const int kxA[8] = {-1, 0, 1,-1, 1,-1, 0, 1};
    float dot[8], nn[8];
#pragma unroll
    for (int n = 0; n < 8; n++) {
        int hn = hh + kyA[n], wn = w + kxA[n];
        bool v = (hn >= 0) & (hn < H_) & (wn >= 0) & (wn < W_);
        float msk = v ? 1.f : 0.f;
        const short* nb = xsb + (size_t)(b*HW_ + min(max(hn,0),H_-1)*W_ + min(max(wn,0),W_-1))*XC_ + q*16;
        float d = 0.f, s2 = 0.f;
#pragma unroll
        for (int s = 0; s < 2; s++) {
            bf16x8 qb = *reinterpret_cast<const bf16x8*>(nb + s*8);
#pragma unroll
            for (int j = 0; j < 8; j++) {
                float vv = b2f(qb[j]) * msk;
                d  = fmaf(cv[s*8+j], vv, d);
                s2 = fmaf(vv, vv, s2);
            }
        }
        dot[n] = d; nn[n] = s2;
    }
    ncc += __shfl_xor(ncc, 1); ncc += __shfl_xor(ncc, 2);
    const float ncr = 1.f / fmaxf(sqrtf(ncc), EPS_);
    float res[8];
#pragma unroll
    for (int n = 0; n < 8; n++) {
        float dt = dot[n]; dt += __shfl_xor(dt, 1); dt += __shfl_xor(dt, 2);
        float s2 = nn[n];  s2 += __shfl_xor(s2, 1); s2 += __shfl_xor(s2, 2);
        res[n] = dt * ncr / fmaxf(sqrtf(s2), EPS_);
    }
    if (q < 2) {
        bf16x4 r = { f2bf_s(res[q*4]),   f2bf_s(res[q*4+1]),
                     f2bf_s(res[q*4+2]), f2bf_s(res[q*4+3]) };
        *reinterpret_cast<bf16x4*>(xsb + (size_t)px * XC_ + 64 + q*4) = r;
    }
}

// ---------------------------------------------------------------------------
// cmdcn: FUSED cm (3x3 conv 72->27 -> offsets/mask) + dcn (deform conv).
// Block = 64 px, 4 waves, grid 1280. Phase 1: cm MFMA GEMM -> om_l LDS
// (stride 29: conflict-free). One barrier. Phase 2: dcn MFMA GEMM with
// bilinear meta read from LDS, W coalesced from L2 (wlin), 2-deep GA/GB
// gather ping-pong. Deletes om's 9.2MB HBM write + read + a launch.
// ---------------------------------------------------------------------------
__global__ __launch_bounds__(256, 3) void cmdcn_kernel(const short* __restrict__ xsb,
                                                       const short* __restrict__ cwL,
                                                       const float* __restrict__ cmb,
                                                       const short* __restrict__ wlin,
                                                       const float* __restrict__ bias,
                                                       float* __restrict__ out)
{
    __shared__ float om_l[64][29];

    const int t  = threadIdx.x;
    const int wg = blockIdx.x;
    const int sw = (wg & 7) * 160 + (wg >> 3);              // XCD-contiguous
    const int px0 = sw * 64;
    const int lane = t & 63, wv = t >> 6;
    const int fr = lane & 15, fq = lane >> 4;

    const int pxs = px0 + wv*16 + fr;
    const int wsx = pxs % W_, hs = (pxs / W_) % H_, bs = pxs / HW_;
    const size_t xrow = (size_t)bs * HW_;

    // ================= phase 1: cm =================
    {
        f32x4 acc[2];
        acc[0] = (f32x4){0.f,0.f,0.f,0.f};
        acc[1] = (f32x4){0.f,0.f,0.f,0.f};

        bf16x8 G8; bf16x8 WF[2]; bool mskb;

#define CM_ISSUE_G(CH) do {                                                   \
    int k0_ = (CH)*32 + fq*8;                                                 \
    int tap_ = (k0_ * 911) >> 16;                                             \
    bool valid_ = (tap_ < 9);                                                 \
    tap_ = min(tap_, 8);                                                      \
    int ch_ = min(max(k0_ - tap_*72, 0), 64);                                 \
    int t3_ = (tap_ * 11) >> 5;                                               \
    int hy_ = hs + t3_ - 1, wx_ = wsx + (tap_ - t3_*3) - 1;                   \
    bool v_ = (hy_ >= 0) & (hy_ < H_) & (wx_ >= 0) & (wx_ < W_);              \
    mskb = v_ & valid_;                                                       \
    const short* src_ = xsb + (size_t)(xrow + min(max(hy_,0),H_-1)*W_         \
                                       + min(max(wx_,0),W_-1))*XC_ + ch_;     \
    G8 = *reinterpret_cast<const bf16x8*>(src_);                              \
  } while(0)

#define CM_ISSUE_W(CH) do {                                                   \
    const short* wp_ = cwL + (CH)*1024 + lane*8;                              \
    WF[0] = *reinterpret_cast<const bf16x8*>(wp_);                            \
    WF[1] = *reinterpret_cast<const bf16x8*>(wp_ + 512);                      \
  } while(0)

        CM_ISSUE_G(0);
        CM_ISSUE_W(0);

#pragma unroll 1
        for (int c = 0; c < NCH_; c++) {
            bf16x8 zero8 = {0,0,0,0,0,0,0,0};
            bf16x8 AF = mskb ? G8 : zero8;                  // exact binary mask
            bf16x8 W0 = WF[0], W1 = WF[1];
            if (c < NCH_-1) { CM_ISSUE_G(c+1); CM_ISSUE_W(c+1); }
            acc[0] = __builtin_amdgcn_mfma_f32_16x16x32_bf16(AF, W0, acc[0], 0,0,0);
            acc[1] = __builtin_amdgcn_mfma_f32_16x16x32_bf16(AF, W1, acc[1], 0,0,0);
        }

        // epilogue -> LDS: row px = wv*16 + fq*4 + r, col o = j*16 + fr
        const int rl = wv*16 + fq*4;
#pragma unroll
        for (int j = 0; j < 2; j++) {
            int o = j*16 + fr;
            if (o < 27) {
                float bv = cmb[o];
#pragma unroll
                for (int r = 0; r < 4; r++)
                    om_l[rl + r][o] = acc[j][r] + bv;
            }
        }
    }
    __syncthreads();

    // ================= phase 2: dcn =================
    const int ce = fq * 8;
    const int rp = wv*16 + fr;                              // this lane's px row
    const int lb = lane*8;

    f32x4 acc[4];
#pragma unroll
    for (int j = 0; j < 4; j++) acc[j] = (f32x4){0.f,0.f,0.f,0.f};

#define DCN_META(KK, W00, W01, W10, W11, P0, P1, P2, P3) do {                 \
    float dy_ = om_l[rp][2*(KK)], dx_ = om_l[rp][2*(KK)+1];                   \
    float mz_ = om_l[rp][18+(KK)];                                            \
    float m_  = 1.f / (1.f + __expf(-mz_));                                   \
    float py_ = (float)(hs + (KK)/3 - 1) + dy_;                               \
    float px_ = (float)(wsx + (KK)%3 - 1) + dx_;                              \
    float y0f_ = floorf(py_), x0f_ = floorf(px_);                             \
    int   y0_ = (int)y0f_,   x0_ = (int)x0f_;                                 \
    float wy_ = py_ - y0f_,  wx_ = px_ - x0f_;                                \
    bool vy0_ = (y0_ >= 0)  & (y0_ < H_);                                     \
    bool vy1_ = (y0_ >= -1) & (y0_ < H_ - 1);                                 \
    bool vx0_ = (x0_ >= 0)  & (x0_ < W_);                                     \
    bool vx1_ = (x0_ >= -1) & (x0_ < W_ - 1);                                 \
    W00 = (1.f-wy_)*(1.f-wx_)*m_*((vy0_&vx0_)?1.f:0.f);                       \
    W01 = (1.f-wy_)*wx_      *m_*((vy0_&vx1_)?1.f:0.f);                       \
    W10 = wy_*(1.f-wx_)      *m_*((vy1_&vx0_)?1.f:0.f);                       \
    W11 = wy_*wx_            *m_*((vy1_&vx1_)?1.f:0.f);                       \
    int y0c_ = min(max(y0_,   0), H_-1), y1c_ = min(max(y0_+1, 0), H_-1);     \
    int x0c_ = min(max(x0_,   0), W_-1), x1c_ = min(max(x0_+1, 0), W_-1);     \
    P0 = xsb + (size_t)(xrow + y0c_*W_ + x0c_)*XC_ + ce;                      \
    P1 = xsb + (size_t)(xrow + y0c_*W_ + x1c_)*XC_ + ce;                      \
    P2 = xsb + (size_t)(xrow + y1c_*W_ + x0c_)*XC_ + ce;                      \
    P3 = xsb + (size_t)(xrow + y1c_*W_ + x1c_)*XC_ + ce;                      \
  } while(0)

#define DCN_GATHER(G, P0, P1, P2, P3) do {                                    \
    G[0] = *reinterpret_cast<const bf16x8*>(P0);                              \
    G[1] = *reinterpret_cast<const bf16x8*>(P0 + 32);                         \
    G[2] = *reinterpret_cast<const bf16x8*>(P1);                              \
    G[3] = *reinterpret_cast<const bf16x8*>(P1 + 32);                         \
    G[4] = *reinterpret_cast<const bf16x8*>(P2);                              \
    G[5] = *reinterpret_cast<const bf16x8*>(P2 + 32);                         \
    G[6] = *reinterpret_cast<const bf16x8*>(P3);                              \
    G[7] = *reinterpret_cast<const bf16x8*>(P3 + 32);                         \
  } while(0)

#define DCN_WLOAD(KK, WF) do {                                                \
    const short* wp_ = wlin + (KK)*4096 + lb;                                 \
    WF[0] = *reinterpret_cast<const bf16x8*>(wp_);                            \
    WF[1] = *reinterpret_cast<const bf16x8*>(wp_ + 512);                      \
    WF[2] = *reinterpret_cast<const bf16x8*>(wp_ + 1024);                     \
    WF[3] = *reinterpret_cast<const bf16x8*>(wp_ + 1536);                     \
    WF[4] = *reinterpret_cast<const bf16x8*>(wp_ + 2048);                     \
    WF[5] = *reinterpret_cast<const bf16x8*>(wp_ + 2560);                     \
    WF[6] = *reinterpret_cast<const bf16x8*>(wp_ + 3072);                     \
    WF[7] = *reinterpret_cast<const bf16x8*>(wp_ + 3584);                     \
  } while(0)

#define DCN_COMBINE(G, W00, W01, W10, W11, AA, AB) do {                       \
    _Pragma("unroll")                                                         \
    for (int e_ = 0; e_ < 8; e_++)                                            \
        AA[e_] = f2bf_s(W00*b2f(G[0][e_]) + W01*b2f(G[2][e_])                 \
                      + W10*b2f(G[4][e_]) + W11*b2f(G[6][e_]));               \
    _Pragma("unroll")                                                         \
    for (int e_ = 0; e_ < 8; e_++)                                            \
        AB[e_] = f2bf_s(W00*b2f(G[1][e_]) + W01*b2f(G[3][e_])                 \
                      + W10*b2f(G[5][e_]) + W11*b2f(G[7][e_]));               \
  } while(0)

#define DCN_MFMA(WF, AA, AB) do {                                             \
    acc[0] = __builtin_amdgcn_mfma_f32_16x16x32_bf16(AA, WF[0], acc[0],0,0,0);\
    acc[0] = __builtin_amdgcn_mfma_f32_16x16x32_bf16(AB, WF[1], acc[0],0,0,0);\
    acc[1] = __builtin_amdgcn_mfma_f32_16x16x32_bf16(AA, WF[2], acc[1],0,0,0);\
    acc[1] = __builtin_amdgcn_mfma_f32_16x16x32_bf16(AB, WF[3], acc[1],0,0,0);\
    acc[2] = __builtin_amdgcn_mfma_f32_16x16x32_bf16(AA, WF[4], acc[2],0,0,0);\
    acc[2] = __builtin_amdgcn_mfma_f32_16x16x32_bf16(AB, WF[5], acc[2],0,0,0);\
    acc[3] = __builtin_amdgcn_mfma_f32_16x16x32_bf16(AA, WF[6], acc[3],0,0,0);\
    acc[3] = __builtin_amdgcn_mfma_f32_16x16x32_bf16(AB, WF[7], acc[3],0,0,0);\
  } while(0)

    // ---- prologue: GA(0) in flight; meta(1) ready ----
    float wA00, wA01, wA10, wA11; const short *pA0, *pA1, *pA2, *pA3;
    float wB00, wB01, wB10, wB11; const short *pB0, *pB1, *pB2, *pB3;
    bf16x8 GA[8], GB[8];

    DCN_META(0, wA00,wA01,wA10,wA11, pA0,pA1,pA2,pA3);
    DCN_GATHER(GA, pA0,pA1,pA2,pA3);
    DCN_META(1, wB00,wB01,wB10,wB11, pB0,pB1,pB2,pB3);

#pragma unroll 1
    for (int kp = 0; kp < 4; kp++) {
        const int ke = kp*2;
        // ---- tap ke (even): GA holds data, wA holds weights ----
        DCN_GATHER(GB, pB0,pB1,pB2,pB3);                // tap ke+1 in flight
        bf16x8 WE[8]; DCN_WLOAD(ke, WE);                // coalesced L2
        float nA00,nA01,nA10,nA11; const short *qA0,*qA1,*qA2,*qA3;
        DCN_META(ke+2, nA00,nA01,nA10,nA11, qA0,qA1,qA2,qA3);   // ke+2 <= 8
        bf16x8 aA, aB; DCN_COMBINE(GA, wA00,wA01,wA10,wA11, aA, aB);
        DCN_MFMA(WE, aA, aB);
        wA00=nA00; wA01=nA01; wA10=nA10; wA11=nA11;
        pA0=qA0; pA1=qA1; pA2=qA2; pA3=qA3;
        DCN_GATHER(GA, pA0,pA1,pA2,pA3);                // tap ke+2 in flight

        // ---- tap ke+1 (odd): GB holds data, wB holds weights ----
        bf16x8 WO[8]; DCN_WLOAD(ke+1, WO);
        float nB00,nB01,nB10,nB11; const short *qB0,*qB1,*qB2,*qB3;
        if (kp < 3) {
            DCN_META(ke+3, nB00,nB01,nB10,nB11, qB0,qB1,qB2,qB3);
        } else {
            nB00=wB00; nB01=wB01; nB10=wB10; nB11=wB11;
            qB0=pB0; qB1=pB1; qB2=pB2; qB3=pB3;
        }
        bf16x8 cA, cB; DCN_COMBINE(GB, wB00,wB01,wB10,wB11, cA, cB);
        DCN_MFMA(WO, cA, cB);
        wB00=nB00; wB01=nB01; wB10=nB10; wB11=nB11;
        pB0=qB0; pB1=qB1; pB2=qB2; pB3=qB3;
    }

    // ---- tap 8 (in GA / wA) ----
    {
        bf16x8 WE[8]; DCN_WLOAD(8, WE);
        bf16x8 aA, aB; DCN_COMBINE(GA, wA00,wA01,wA10,wA11, aA, aB);
        DCN_MFMA(WE, aA, aB);
    }

    // ---- epilogue: D row px = wv*16 + fq*4 + reg, col o = j*16 + fr ----
    const int bo = px0 / HW_, po = px0 % HW_;
#pragma unroll
    for (int j = 0; j < 4; j++) {
        int o = j*16 + fr;
        float bv = bias[o];
        f4 r = { acc[j][0] + bv, acc[j][1] + bv, acc[j][2] + bv, acc[j][3] + bv };
        *reinterpret_cast<f4*>(&out[((size_t)(bo*64 + o))*HW_ + po + wv*16 + fq*4]) = r;
    }
}

// ---------------------------------------------------------------------------
extern "C" void kernel_launch(void* const* d_in, const int* in_sizes, int n_in,
                              void* d_out, int out_size, void* d_ws, size_t ws_size,
                              hipStream_t stream)
{
    const float* x   = (const float*)d_in[0];
    const float* wt  = (const float*)d_in[1];
    const float* bs  = (const float*)d_in[2];
    const float* cmw = (const float*)d_in[3];
    const float* cmb = (const float*)d_in[4];
    float* out = (float*)d_out;

    short* xsb  = (short*)d_ws;                             // NPIX_*72 bf16
    short* wlin = xsb + (size_t)NPIX_ * XC_;                // 9*4096 bf16
    short* cwL  = wlin + 9*4096;                            // 21*1024 bf16

    prep_kernel <<<228, 256, 0, stream>>>(wt, cmw, wlin, cwL);
    xpose_kernel<<<NPIX_/128, 128, 0, stream>>>(x, xsb);
    sim_kernel  <<<NPIX_/16,  64,  0, stream>>>(xsb);
    cmdcn_kernel<<<NPIX_/64,  256, 0, stream>>>(xsb, cwL, cmb, wlin, bs, out);
}